// Round 6
// baseline (316.085 us; speedup 1.0000x reference)
//
#include <hip/hip_runtime.h>
#include <hip/hip_bf16.h>
#include <cstdint>
#include <cstddef>

#define BB 4
#define NN 4096
#define EE 65536
#define HID 128
#define FN 32
#define FE 16
#define NROUNDS 3

#define XP 296   // edge X row pitch (bf16): 288 data + 8 pad
#define XNP 264  // node X row pitch (bf16): 256 data + 8 pad
#define PP 136   // P row pitch (bf16): 128 data + 8 pad
#define RP 132   // reduction tile row pitch (fp32): 128 data + 4 pad

typedef __attribute__((ext_vector_type(8))) short short8;
typedef __attribute__((ext_vector_type(4))) float f32x4;
typedef unsigned int uint_t;

// h lives inside d_out: node n of batch b at out[(b*(NN+1) + 1 + n)*HID + j].
__device__ __forceinline__ size_t hrow(int b, int n) {
    return ((size_t)b * (NN + 1) + 1 + n) * HID;
}

__device__ __forceinline__ short f2bf(float f) {   // RNE float->bf16
    union { float f; uint32_t u; } v; v.f = f;
    uint32_t r = v.u + 0x7FFFu + ((v.u >> 16) & 1u);
    return (short)(r >> 16);
}

// fast silu: native exp + v_rcp (error << bf16 rounding of downstream use)
__device__ __forceinline__ float silu(float x) {
    return x * __builtin_amdgcn_rcpf(1.0f + __expf(-x));
}

__device__ __forceinline__ int clipn(int x) {
    return x < 0 ? 0 : (x > NN - 1 ? NN - 1 : x);
}

// ---------------- h0 = nodes @ W_node; writes fp32 h (in out) + bf16 shadow
__global__ void proj_nodes_kernel(const float* __restrict__ nodes,
                                  const float* __restrict__ Wn,
                                  float* __restrict__ hbuf,
                                  short* __restrict__ hbf) {
    __shared__ float nd[8][FN];
    int t = threadIdx.x;
    int row0 = blockIdx.x * 8;
    for (int i = 0; i < 2; ++i) {
        int idx = i * 128 + t; int r = idx >> 5; int c = idx & 31;
        nd[r][c] = nodes[(size_t)(row0 + r) * FN + c];
    }
    __syncthreads();
    float acc[8] = {0.f,0.f,0.f,0.f,0.f,0.f,0.f,0.f};
    #pragma unroll
    for (int k = 0; k < FN; ++k) {
        float w = Wn[k * HID + t];
        #pragma unroll
        for (int r = 0; r < 8; ++r) acc[r] += nd[r][k] * w;
    }
    #pragma unroll
    for (int r = 0; r < 8; ++r) {
        int row = row0 + r; int b = row >> 12; int n = row & (NN - 1);
        hbuf[hrow(b, n) + t] = acc[r];
        hbf[(size_t)row * HID + t] = f2bf(acc[r]);
    }
}

// ---- Wec[r] = W_edge (16x128) @ eW1[r][256:384] (128x128) -> (16x128) fp32
__global__ void fuse_wec_kernel(const float* __restrict__ We,
                                const float* __restrict__ eW1,
                                float* __restrict__ Wec) {
    int t = threadIdx.x;
    int i = blockIdx.x & 15;
    int r = blockIdx.x >> 4;
    const float* w1 = eW1 + ((size_t)r * 384 + 256) * HID;
    float acc = 0.f;
    for (int k = 0; k < HID; ++k)
        acc += We[i * HID + k] * w1[k * HID + t];
    Wec[((size_t)r * 16 + i) * HID + t] = acc;
}

// ---------------- marker rows of the output --------------------------------
__global__ void marker_kernel(const float* __restrict__ marker,
                              float* __restrict__ out) {
    int t = threadIdx.x;
    int b = t >> 7; int j = t & 127;
    out[((size_t)b * (NN + 1)) * HID + j] = marker[j];
}

// ---- generic weight pack: (R, K, 128) fp32 -> per-lane B-fragment bf16 ----
__global__ void pack_w_kernel(const float* __restrict__ W,
                              short* __restrict__ P,
                              int KT, int rstrideW) {
    int lane = threadIdx.x;
    int nt = blockIdx.x & 7;
    int kt = (blockIdx.x >> 3) % KT;
    int r  = blockIdx.x / (8 * KT);
    const float* Wr = W + (size_t)r * rstrideW;
    int n  = nt * 16 + (lane & 15);
    int k0 = kt * 32 + (lane >> 4) * 8;
    short v[8];
    #pragma unroll
    for (int i = 0; i < 8; ++i) v[i] = f2bf(Wr[(size_t)(k0 + i) * HID + n]);
    size_t idx = (((size_t)(r * KT + kt) * 8 + nt) * 64 + lane) * 8;
    *(uint4*)&P[idx] = *(uint4*)v;
}

// ---- edge layer-1 pack: K=288 = eW1 rows 0..255 | Wec rows 0..15 | zeros --
__global__ void pack_e1_kernel(const float* __restrict__ eW1,
                               const float* __restrict__ Wec,
                               short* __restrict__ P) {
    const int KT = 9;
    int lane = threadIdx.x;
    int nt = blockIdx.x & 7;
    int kt = (blockIdx.x >> 3) % KT;
    int r  = blockIdx.x / (8 * KT);
    int n  = nt * 16 + (lane & 15);
    int k0 = kt * 32 + (lane >> 4) * 8;
    short v[8];
    #pragma unroll
    for (int i = 0; i < 8; ++i) {
        int k = k0 + i;
        float x;
        if (k < 256)      x = eW1[((size_t)r * 384 + k) * HID + n];
        else if (k < 272) x = Wec[((size_t)r * 16 + (k - 256)) * HID + n];
        else              x = 0.f;
        v[i] = f2bf(x);
    }
    size_t idx = (((size_t)(r * KT + kt) * 8 + nt) * 64 + lane) * 8;
    *(uint4*)&P[idx] = *(uint4*)v;
}

// ================= counting sort of edges by (b, dst) ======================
__global__ void hist_kernel(const int* __restrict__ edges,
                            uint_t* __restrict__ cnt) {
    int i = blockIdx.x * 256 + threadIdx.x;
    int b = i >> 16;
    int d = clipn(edges[(size_t)i * 2 + 1]);
    atomicAdd(&cnt[b * NN + d], 1u);
}

// one block, 256 threads: exclusive scan of 16384 counts -> cursor
__global__ void scan_kernel(const uint_t* __restrict__ cnt,
                            uint_t* __restrict__ cursor) {
    __shared__ uint_t ps[256];
    int t = threadIdx.x;
    int base = t * 64;
    uint_t s = 0;
    for (int i = 0; i < 64; ++i) s += cnt[base + i];
    ps[t] = s;
    __syncthreads();
    for (int off = 1; off < 256; off <<= 1) {
        uint_t v = (t >= off) ? ps[t - off] : 0u;
        __syncthreads();
        ps[t] += v;
        __syncthreads();
    }
    uint_t run = ps[t] - s;
    for (int i = 0; i < 64; ++i) {
        cursor[base + i] = run;
        run += cnt[base + i];
    }
}

__global__ void scatter_kernel(const int* __restrict__ edges,
                               uint_t* __restrict__ cursor,
                               uint_t* __restrict__ eidx) {
    int i = blockIdx.x * 256 + threadIdx.x;
    int b = i >> 16;
    int d = clipn(edges[(size_t)i * 2 + 1]);
    uint_t p = atomicAdd(&cursor[b * NN + d], 1u);
    eidx[p] = (uint_t)(i & (EE - 1));
}

// ---- pre-permute edge data into sorted order (once; reused 3 rounds) ------
// meta[p] = src | dst<<12 | mask<<24 ; efs[p][0..15] = bf16 edge features
__global__ void permute_kernel(const int* __restrict__ edges,
                               const int* __restrict__ emask,
                               const float* __restrict__ edge_feat,
                               const uint_t* __restrict__ eidx,
                               uint_t* __restrict__ meta,
                               short* __restrict__ efs) {
    int p = blockIdx.x * 256 + threadIdx.x;       // global sorted position
    int b = p >> 16;
    int e = (int)eidx[p];
    int2 pr = *(const int2*)&edges[((size_t)b * EE + e) * 2];
    int s = clipn(pr.x), d = clipn(pr.y);
    uint_t mk = emask[(size_t)b * EE + e] ? 1u : 0u;
    meta[p] = (uint_t)s | ((uint_t)d << 12) | (mk << 24);
    const float* src = edge_feat + ((size_t)b * EE + e) * FE;
    short v[16];
    #pragma unroll
    for (int i = 0; i < 16; ++i) v[i] = f2bf(src[i]);
    *(uint4*)(efs + (size_t)p * FE)     = *(uint4*)v;
    *(uint4*)(efs + (size_t)p * FE + 8) = *(uint4*)(v + 8);
}

// ===== edge MLP (MFMA) over dst-sorted edges + segment-reduced scatter =====
__global__ __launch_bounds__(256, 4)
void edge_mfma_csr_kernel(const short* __restrict__ hbf,
                          const short* __restrict__ efs,
                          const uint_t* __restrict__ meta,
                          const short* __restrict__ W1p,
                          const short* __restrict__ W2p,
                          const float* __restrict__ b1,
                          const float* __restrict__ b2,
                          float* __restrict__ agg) {
    // one buffer, three aliased phases: X (bf16 64xXP) -> P (bf16 64xPP)
    //                                   -> Rt (fp32 64xRP)
    __shared__ short X[64 * XP];                   // 37888 B
    __shared__ int ssrc[64];
    __shared__ int sdst[64];
    __shared__ float smf[64];
    short* Pl = X;
    float* Rt = (float*)X;

    int t = threadIdx.x;
    int p0 = blockIdx.x * 64;                      // sorted-position base
    int b  = p0 >> 16;

    if (t < 64) {
        uint_t m = meta[p0 + t];
        ssrc[t] = (int)(m & 0xFFFu);
        sdst[t] = (int)((m >> 12) & 0xFFFu);
        smf[t]  = (m >> 24) ? 1.f : 0.f;
    }
    __syncthreads();

    // stage h_src (cols 0..127): 64 rows x 16 chunks of 16B
    #pragma unroll
    for (int i = 0; i < 4; ++i) {
        int c = i * 256 + t; int e = c >> 4; int s = c & 15;
        uint4 v = *(const uint4*)(hbf + ((size_t)b * NN + ssrc[e]) * HID + s * 8);
        *(uint4*)((char*)X + e * (XP * 2) + s * 16) = v;
    }
    // stage h_dst (cols 128..255) — sorted: consecutive rows often same dst
    #pragma unroll
    for (int i = 0; i < 4; ++i) {
        int c = i * 256 + t; int e = c >> 4; int s = c & 15;
        uint4 v = *(const uint4*)(hbf + ((size_t)b * NN + sdst[e]) * HID + s * 8);
        *(uint4*)((char*)X + e * (XP * 2) + 256 + s * 16) = v;
    }
    if (t < 128) {  // bf16 edge feats (cols 256..271): contiguous 2 KB
        int e = t >> 1; int s = t & 1;
        uint4 v = *(const uint4*)(efs + (size_t)(p0 + e) * FE + s * 8);
        *(uint4*)((char*)X + e * (XP * 2) + 512 + s * 16) = v;
    }
    if (t < 128) {  // zero K-pad cols 272..287
        int e = t >> 1; int s = t & 1;
        *(uint4*)((char*)X + e * (XP * 2) + 544 + s * 16) = make_uint4(0,0,0,0);
    }
    __syncthreads();

    int lane = t & 63;
    int w    = t >> 6;
    int m0 = (w & 1) * 32;
    int n0 = (w >> 1) * 64;
    int lr = lane & 15;
    int lg = lane >> 4;

    // ---------------- layer 1: (64x288) @ (288x128) ----------------
    f32x4 acc[2][4];
    #pragma unroll
    for (int nf = 0; nf < 4; ++nf) {
        float bv = b1[n0 + nf * 16 + lr];
        #pragma unroll
        for (int mf = 0; mf < 2; ++mf)
            acc[mf][nf] = (f32x4){bv, bv, bv, bv};
    }
    const char* Xb = (const char*)X;
    for (int kt = 0; kt < 9; ++kt) {
        short8 a[2];
        #pragma unroll
        for (int mf = 0; mf < 2; ++mf)
            a[mf] = *(const short8*)(Xb + (m0 + mf * 16 + lr) * (XP * 2)
                                        + (kt * 32 + lg * 8) * 2);
        const short* wp = W1p + (((size_t)kt * 8 + (n0 >> 4)) * 64 + lane) * 8;
        #pragma unroll
        for (int nf = 0; nf < 4; ++nf) {
            short8 bf = *(const short8*)(wp + (size_t)nf * 64 * 8);
            #pragma unroll
            for (int mf = 0; mf < 2; ++mf)
                acc[mf][nf] = __builtin_amdgcn_mfma_f32_16x16x32_bf16(
                    a[mf], bf, acc[mf][nf], 0, 0, 0);
        }
    }
    __syncthreads();   // done reading X; overwrite with P

    #pragma unroll
    for (int mf = 0; mf < 2; ++mf)
        #pragma unroll
        for (int nf = 0; nf < 4; ++nf)
            #pragma unroll
            for (int r = 0; r < 4; ++r) {
                int row = m0 + mf * 16 + lg * 4 + r;
                int col = n0 + nf * 16 + lr;
                Pl[row * PP + col] = f2bf(silu(acc[mf][nf][r]));
            }
    __syncthreads();

    // ---------------- layer 2: (64x128) @ (128x128) ----------------
    f32x4 acc2[2][4];
    #pragma unroll
    for (int nf = 0; nf < 4; ++nf) {
        float bv = b2[n0 + nf * 16 + lr];
        #pragma unroll
        for (int mf = 0; mf < 2; ++mf)
            acc2[mf][nf] = (f32x4){bv, bv, bv, bv};
    }
    const char* Pb = (const char*)Pl;
    for (int kt = 0; kt < 4; ++kt) {
        short8 a[2];
        #pragma unroll
        for (int mf = 0; mf < 2; ++mf)
            a[mf] = *(const short8*)(Pb + (m0 + mf * 16 + lr) * (PP * 2)
                                        + (kt * 32 + lg * 8) * 2);
        const short* wp = W2p + (((size_t)kt * 8 + (n0 >> 4)) * 64 + lane) * 8;
        #pragma unroll
        for (int nf = 0; nf < 4; ++nf) {
            short8 bf = *(const short8*)(wp + (size_t)nf * 64 * 8);
            #pragma unroll
            for (int mf = 0; mf < 2; ++mf)
                acc2[mf][nf] = __builtin_amdgcn_mfma_f32_16x16x32_bf16(
                    a[mf], bf, acc2[mf][nf], 0, 0, 0);
        }
    }
    __syncthreads();   // done reading P; overwrite with Rt (fp32 msg tile)

    #pragma unroll
    for (int mf = 0; mf < 2; ++mf)
        #pragma unroll
        for (int r = 0; r < 4; ++r) {
            int row = m0 + mf * 16 + lg * 4 + r;
            float m = smf[row];
            #pragma unroll
            for (int nf = 0; nf < 4; ++nf)
                Rt[row * RP + n0 + nf * 16 + lr] = acc2[mf][nf][r] * m;
        }
    __syncthreads();

    // segment-reduce contiguous same-dst rows; one atomic per segment
    {
        int half = t >> 7;            // rows 0..31 or 32..63
        int c    = t & 127;
        int r0 = half * 32, r1 = r0 + 32;
        float run = 0.f;
        int cur = sdst[r0];
        for (int r = r0; r < r1; ++r) {
            int d = sdst[r];          // wave-uniform
            if (d != cur) {
                atomicAdd(&agg[((size_t)b * NN + cur) * HID + c], run);
                run = 0.f; cur = d;
            }
            run += Rt[r * RP + c];
        }
        atomicAdd(&agg[((size_t)b * NN + cur) * HID + c], run);
    }
}

// ------------- node MLP (MFMA) + residual + mask.  64 rows / block ---------
__global__ __launch_bounds__(256, 4)
void node_mfma_kernel(const short* __restrict__ hbf_in,
                      const float* __restrict__ agg,
                      const int* __restrict__ nmask,
                      const short* __restrict__ W1p,
                      const short* __restrict__ W2p,
                      const float* __restrict__ b1,
                      const float* __restrict__ b2,
                      float* __restrict__ hout,
                      short* __restrict__ hbf_out) {
    __shared__ short X[64 * XNP];
    __shared__ int smk[64];
    short* Pl = X;

    int t = threadIdx.x;
    int row0 = blockIdx.x * 64;
    int b  = row0 >> 12;
    int nn0 = row0 & (NN - 1);

    if (t < 64) smk[t] = nmask[row0 + t];

    #pragma unroll
    for (int i = 0; i < 4; ++i) {
        int c = i * 256 + t; int e = c >> 4; int s = c & 15;
        uint4 v = *(const uint4*)(hbf_in + (size_t)(row0 + e) * HID + s * 8);
        *(uint4*)((char*)X + e * (XNP * 2) + s * 16) = v;
    }
    #pragma unroll
    for (int i = 0; i < 8; ++i) {
        int c = i * 256 + t; int e = c >> 5; int s = c & 31;
        float4 f = *(const float4*)(agg + (size_t)(row0 + e) * HID + s * 4);
        short v[4] = { f2bf(f.x), f2bf(f.y), f2bf(f.z), f2bf(f.w) };
        *(uint2*)((char*)X + e * (XNP * 2) + 256 + s * 8) = *(uint2*)v;
    }
    __syncthreads();

    int lane = t & 63;
    int w    = t >> 6;
    int m0 = (w & 1) * 32;
    int n0 = (w >> 1) * 64;
    int lr = lane & 15;
    int lg = lane >> 4;

    f32x4 acc[2][4];
    #pragma unroll
    for (int nf = 0; nf < 4; ++nf) {
        float bv = b1[n0 + nf * 16 + lr];
        #pragma unroll
        for (int mf = 0; mf < 2; ++mf)
            acc[mf][nf] = (f32x4){bv, bv, bv, bv};
    }
    const char* Xb = (const char*)X;
    for (int kt = 0; kt < 8; ++kt) {
        short8 a[2];
        #pragma unroll
        for (int mf = 0; mf < 2; ++mf)
            a[mf] = *(const short8*)(Xb + (m0 + mf * 16 + lr) * (XNP * 2)
                                        + (kt * 32 + lg * 8) * 2);
        const short* wp = W1p + (((size_t)kt * 8 + (n0 >> 4)) * 64 + lane) * 8;
        #pragma unroll
        for (int nf = 0; nf < 4; ++nf) {
            short8 bf = *(const short8*)(wp + (size_t)nf * 64 * 8);
            #pragma unroll
            for (int mf = 0; mf < 2; ++mf)
                acc[mf][nf] = __builtin_amdgcn_mfma_f32_16x16x32_bf16(
                    a[mf], bf, acc[mf][nf], 0, 0, 0);
        }
    }
    __syncthreads();

    #pragma unroll
    for (int mf = 0; mf < 2; ++mf)
        #pragma unroll
        for (int nf = 0; nf < 4; ++nf)
            #pragma unroll
            for (int r = 0; r < 4; ++r) {
                int row = m0 + mf * 16 + lg * 4 + r;
                int col = n0 + nf * 16 + lr;
                Pl[row * PP + col] = f2bf(silu(acc[mf][nf][r]));
            }
    __syncthreads();

    f32x4 acc2[2][4];
    #pragma unroll
    for (int nf = 0; nf < 4; ++nf) {
        float bv = b2[n0 + nf * 16 + lr];
        #pragma unroll
        for (int mf = 0; mf < 2; ++mf)
            acc2[mf][nf] = (f32x4){bv, bv, bv, bv};
    }
    const char* Pb = (const char*)Pl;
    for (int kt = 0; kt < 4; ++kt) {
        short8 a[2];
        #pragma unroll
        for (int mf = 0; mf < 2; ++mf)
            a[mf] = *(const short8*)(Pb + (m0 + mf * 16 + lr) * (PP * 2)
                                        + (kt * 32 + lg * 8) * 2);
        const short* wp = W2p + (((size_t)kt * 8 + (n0 >> 4)) * 64 + lane) * 8;
        #pragma unroll
        for (int nf = 0; nf < 4; ++nf) {
            short8 bf = *(const short8*)(wp + (size_t)nf * 64 * 8);
            #pragma unroll
            for (int mf = 0; mf < 2; ++mf)
                acc2[mf][nf] = __builtin_amdgcn_mfma_f32_16x16x32_bf16(
                    a[mf], bf, acc2[mf][nf], 0, 0, 0);
        }
    }

    #pragma unroll
    for (int mf = 0; mf < 2; ++mf)
        #pragma unroll
        for (int r = 0; r < 4; ++r) {
            int rl = m0 + mf * 16 + lg * 4 + r;
            float m = smk[rl] ? 1.f : 0.f;
            size_t ho = hrow(b, nn0 + rl);
            size_t hb = (size_t)(row0 + rl) * HID;
            #pragma unroll
            for (int nf = 0; nf < 4; ++nf) {
                int col = n0 + nf * 16 + lr;
                float hold = hout[ho + col];
                float hn = (hold + acc2[mf][nf][r]) * m;
                hout[ho + col] = hn;
                hbf_out[hb + col] = f2bf(hn);
            }
        }
}

extern "C" void kernel_launch(void* const* d_in, const int* in_sizes, int n_in,
                              void* d_out, int out_size, void* d_ws, size_t ws_size,
                              hipStream_t stream) {
    const float* nodes     = (const float*)d_in[0];
    const float* edge_feat = (const float*)d_in[1];
    const int*   edges     = (const int*)d_in[2];
    const int*   node_mask = (const int*)d_in[3];
    const int*   edge_mask = (const int*)d_in[4];
    const float* W_node    = (const float*)d_in[5];
    const float* W_edge    = (const float*)d_in[6];
    const float* marker    = (const float*)d_in[7];
    const float* eW1       = (const float*)d_in[8];
    const float* eb1       = (const float*)d_in[9];
    const float* eW2       = (const float*)d_in[10];
    const float* eb2       = (const float*)d_in[11];
    const float* nW1       = (const float*)d_in[12];
    const float* nb1       = (const float*)d_in[13];
    const float* nW2       = (const float*)d_in[14];
    const float* nb2       = (const float*)d_in[15];
    float* out = (float*)d_out;

    const size_t HN = (size_t)BB * NN * HID;        // 2,097,152
    char* wsb = (char*)d_ws;
    float*  agg    = (float*)wsb;   wsb += HN * 4;
    short*  hbf    = (short*)wsb;   wsb += HN * 2;
    float*  Wec    = (float*)wsb;   wsb += 3 * 16 * HID * 4;
    short*  W1p    = (short*)wsb;   wsb += 3 * 9 * 4096 * 2;
    short*  W2p    = (short*)wsb;   wsb += 3 * 4 * 4096 * 2;
    short*  nW1p   = (short*)wsb;   wsb += 3 * 8 * 4096 * 2;
    short*  nW2p   = (short*)wsb;   wsb += 3 * 4 * 4096 * 2;
    uint_t* cnt    = (uint_t*)wsb;  wsb += (size_t)BB * NN * 4;
    uint_t* cursor = (uint_t*)wsb;  wsb += (size_t)BB * NN * 4;
    uint_t* eidx   = (uint_t*)wsb;  wsb += (size_t)BB * EE * 4;
    uint_t* meta   = (uint_t*)wsb;  wsb += (size_t)BB * EE * 4;
    short*  efs    = (short*)wsb;   wsb += (size_t)BB * EE * FE * 2;
    if ((size_t)(wsb - (char*)d_ws) > ws_size) return;  // clean fail

    // ---- prolog (once per call) ----
    proj_nodes_kernel<<<(BB * NN) / 8, 128, 0, stream>>>(nodes, W_node, out, hbf);
    fuse_wec_kernel<<<48, 128, 0, stream>>>(W_edge, eW1, Wec);
    marker_kernel<<<1, 512, 0, stream>>>(marker, out);
    pack_e1_kernel<<<3 * 9 * 8, 64, 0, stream>>>(eW1, Wec, W1p);
    pack_w_kernel<<<3 * 4 * 8, 64, 0, stream>>>(eW2, W2p, 4, HID * HID);
    pack_w_kernel<<<3 * 8 * 8, 64, 0, stream>>>(nW1, nW1p, 8, 2 * HID * HID);
    pack_w_kernel<<<3 * 4 * 8, 64, 0, stream>>>(nW2, nW2p, 4, HID * HID);

    // counting sort of edges by (b, dst), then pre-permute edge data
    hipMemsetAsync(cnt, 0, (size_t)BB * NN * 4, stream);
    hist_kernel<<<(BB * EE) / 256, 256, 0, stream>>>(edges, cnt);
    scan_kernel<<<1, 256, 0, stream>>>(cnt, cursor);
    scatter_kernel<<<(BB * EE) / 256, 256, 0, stream>>>(edges, cursor, eidx);
    permute_kernel<<<(BB * EE) / 256, 256, 0, stream>>>(
        edges, edge_mask, edge_feat, eidx, meta, efs);

    for (int r = 0; r < NROUNDS; ++r) {
        hipMemsetAsync(agg, 0, HN * sizeof(float), stream);
        edge_mfma_csr_kernel<<<(BB * EE) / 64, 256, 0, stream>>>(
            hbf, efs, meta,
            W1p + (size_t)r * 9 * 4096,
            W2p + (size_t)r * 4 * 4096,
            eb1 + r * HID,
            eb2 + r * HID,
            agg);
        node_mfma_kernel<<<(BB * NN) / 64, 256, 0, stream>>>(
            hbf, agg, node_mask,
            nW1p + (size_t)r * 8 * 4096,
            nW2p + (size_t)r * 4 * 4096,
            nb1 + r * HID,
            nb2 + r * HID,
            out, hbf);
    }
}

// Round 7
// 277.213 us; speedup vs baseline: 1.1402x; 1.1402x over previous
//
#include <hip/hip_runtime.h>
#include <hip/hip_bf16.h>
#include <cstdint>
#include <cstddef>

#define BB 4
#define NN 4096
#define EE 65536
#define HID 128
#define FN 32
#define FE 16
#define NROUNDS 3

#define XP 168   // edge X row pitch (bf16): 160 data (128 h_src + 16 ef + 16 pad) + 8
#define XNP 264  // node X row pitch (bf16): 256 data + 8 pad
#define PP 136   // P / message row pitch (bf16): 128 data + 8 pad
#define YPITCH 136 // proj_y LDS pitch

typedef __attribute__((ext_vector_type(8))) short short8;
typedef __attribute__((ext_vector_type(4))) float f32x4;
typedef unsigned int uint_t;

// h lives inside d_out: node n of batch b at out[(b*(NN+1) + 1 + n)*HID + j].
__device__ __forceinline__ size_t hrow(int b, int n) {
    return ((size_t)b * (NN + 1) + 1 + n) * HID;
}

__device__ __forceinline__ short f2bf(float f) {   // RNE float->bf16
    union { float f; uint32_t u; } v; v.f = f;
    uint32_t r = v.u + 0x7FFFu + ((v.u >> 16) & 1u);
    return (short)(r >> 16);
}

__device__ __forceinline__ float bf2f(short s) {
    union { uint32_t u; float f; } v;
    v.u = ((uint32_t)(unsigned short)s) << 16;
    return v.f;
}

// fast silu: native exp + v_rcp (error << bf16 rounding of downstream use)
__device__ __forceinline__ float silu(float x) {
    return x * __builtin_amdgcn_rcpf(1.0f + __expf(-x));
}

__device__ __forceinline__ int clipn(int x) {
    return x < 0 ? 0 : (x > NN - 1 ? NN - 1 : x);
}

// ---------------- h0 = nodes @ W_node; writes fp32 h (in out) + bf16 shadow
__global__ void proj_nodes_kernel(const float* __restrict__ nodes,
                                  const float* __restrict__ Wn,
                                  float* __restrict__ hbuf,
                                  short* __restrict__ hbf) {
    __shared__ float nd[8][FN];
    int t = threadIdx.x;
    int row0 = blockIdx.x * 8;
    for (int i = 0; i < 2; ++i) {
        int idx = i * 128 + t; int r = idx >> 5; int c = idx & 31;
        nd[r][c] = nodes[(size_t)(row0 + r) * FN + c];
    }
    __syncthreads();
    float acc[8] = {0.f,0.f,0.f,0.f,0.f,0.f,0.f,0.f};
    #pragma unroll
    for (int k = 0; k < FN; ++k) {
        float w = Wn[k * HID + t];
        #pragma unroll
        for (int r = 0; r < 8; ++r) acc[r] += nd[r][k] * w;
    }
    #pragma unroll
    for (int r = 0; r < 8; ++r) {
        int row = row0 + r; int b = row >> 12; int n = row & (NN - 1);
        hbuf[hrow(b, n) + t] = acc[r];
        hbf[(size_t)row * HID + t] = f2bf(acc[r]);
    }
}

// ---- Wec[r] = W_edge (16x128) @ eW1[r][256:384] (128x128) -> (16x128) fp32
__global__ void fuse_wec_kernel(const float* __restrict__ We,
                                const float* __restrict__ eW1,
                                float* __restrict__ Wec) {
    int t = threadIdx.x;
    int i = blockIdx.x & 15;
    int r = blockIdx.x >> 4;
    const float* w1 = eW1 + ((size_t)r * 384 + 256) * HID;
    float acc = 0.f;
    for (int k = 0; k < HID; ++k)
        acc += We[i * HID + k] * w1[k * HID + t];
    Wec[((size_t)r * 16 + i) * HID + t] = acc;
}

// ---------------- marker rows of the output --------------------------------
__global__ void marker_kernel(const float* __restrict__ marker,
                              float* __restrict__ out) {
    int t = threadIdx.x;
    int b = t >> 7; int j = t & 127;
    out[((size_t)b * (NN + 1)) * HID + j] = marker[j];
}

// ---- generic weight pack: (R, K, 128) fp32 -> per-lane B-fragment bf16 ----
__global__ void pack_w_kernel(const float* __restrict__ W,
                              short* __restrict__ P,
                              int KT, int rstrideW) {
    int lane = threadIdx.x;
    int nt = blockIdx.x & 7;
    int kt = (blockIdx.x >> 3) % KT;
    int r  = blockIdx.x / (8 * KT);
    const float* Wr = W + (size_t)r * rstrideW;
    int n  = nt * 16 + (lane & 15);
    int k0 = kt * 32 + (lane >> 4) * 8;
    short v[8];
    #pragma unroll
    for (int i = 0; i < 8; ++i) v[i] = f2bf(Wr[(size_t)(k0 + i) * HID + n]);
    size_t idx = (((size_t)(r * KT + kt) * 8 + nt) * 64 + lane) * 8;
    *(uint4*)&P[idx] = *(uint4*)v;
}

// ---- edge layer-1 pack: K=160 = eW1 rows 0..127 | Wec 16 rows | zeros -----
__global__ void pack_e1_kernel(const float* __restrict__ eW1,
                               const float* __restrict__ Wec,
                               short* __restrict__ P) {
    const int KT = 5;
    int lane = threadIdx.x;
    int nt = blockIdx.x & 7;
    int kt = (blockIdx.x >> 3) % KT;
    int r  = blockIdx.x / (8 * KT);
    int n  = nt * 16 + (lane & 15);
    int k0 = kt * 32 + (lane >> 4) * 8;
    short v[8];
    #pragma unroll
    for (int i = 0; i < 8; ++i) {
        int k = k0 + i;
        float x;
        if (k < 128)      x = eW1[((size_t)r * 384 + k) * HID + n];
        else if (k < 144) x = Wec[((size_t)r * 16 + (k - 128)) * HID + n];
        else              x = 0.f;
        v[i] = f2bf(x);
    }
    size_t idx = (((size_t)(r * KT + kt) * 8 + nt) * 64 + lane) * 8;
    *(uint4*)&P[idx] = *(uint4*)v;
}

// ================= counting sort of edges by (b, dst) ======================
__global__ void hist_kernel(const int* __restrict__ edges,
                            uint_t* __restrict__ cnt) {
    int i = blockIdx.x * 256 + threadIdx.x;
    int b = i >> 16;
    int d = clipn(edges[(size_t)i * 2 + 1]);
    atomicAdd(&cnt[b * NN + d], 1u);
}

// one block, 256 threads: exclusive scan of 16384 counts -> cursor
__global__ void scan_kernel(const uint_t* __restrict__ cnt,
                            uint_t* __restrict__ cursor) {
    __shared__ uint_t ps[256];
    int t = threadIdx.x;
    int base = t * 64;
    uint_t s = 0;
    for (int i = 0; i < 64; ++i) s += cnt[base + i];
    ps[t] = s;
    __syncthreads();
    for (int off = 1; off < 256; off <<= 1) {
        uint_t v = (t >= off) ? ps[t - off] : 0u;
        __syncthreads();
        ps[t] += v;
        __syncthreads();
    }
    uint_t run = ps[t] - s;
    for (int i = 0; i < 64; ++i) {
        cursor[base + i] = run;
        run += cnt[base + i];
    }
}

__global__ void scatter_kernel(const int* __restrict__ edges,
                               uint_t* __restrict__ cursor,
                               uint_t* __restrict__ eidx) {
    int i = blockIdx.x * 256 + threadIdx.x;
    int b = i >> 16;
    int d = clipn(edges[(size_t)i * 2 + 1]);
    uint_t p = atomicAdd(&cursor[b * NN + d], 1u);
    eidx[p] = (uint_t)(i & (EE - 1));
}

// ---- pre-permute edge data into sorted order (once; reused 3 rounds) ------
// meta[p] = src | dst<<12 | mask<<24 ; efs[p][0..15] = bf16 edge features
__global__ void permute_kernel(const int* __restrict__ edges,
                               const int* __restrict__ emask,
                               const float* __restrict__ edge_feat,
                               const uint_t* __restrict__ eidx,
                               uint_t* __restrict__ meta,
                               short* __restrict__ efs) {
    int p = blockIdx.x * 256 + threadIdx.x;
    int b = p >> 16;
    int e = (int)eidx[p];
    int2 pr = *(const int2*)&edges[((size_t)b * EE + e) * 2];
    int s = clipn(pr.x), d = clipn(pr.y);
    uint_t mk = emask[(size_t)b * EE + e] ? 1u : 0u;
    meta[p] = (uint_t)s | ((uint_t)d << 12) | (mk << 24);
    const float* src = edge_feat + ((size_t)b * EE + e) * FE;
    short v[16];
    #pragma unroll
    for (int i = 0; i < 16; ++i) v[i] = f2bf(src[i]);
    *(uint4*)(efs + (size_t)p * FE)     = *(uint4*)v;
    *(uint4*)(efs + (size_t)p * FE + 8) = *(uint4*)(v + 8);
}

// ---- per-round: Y = h @ eW1[r][128:256] + b1  (bf16 out), 64 rows/block ---
__global__ __launch_bounds__(256, 4)
void proj_y_kernel(const short* __restrict__ hbf,
                   const short* __restrict__ Wp,   // packed, KT=4
                   const float* __restrict__ b1,
                   short* __restrict__ Y) {
    __shared__ short X[64 * YPITCH];
    int t = threadIdx.x;
    int row0 = blockIdx.x * 64;          // global node row

    #pragma unroll
    for (int i = 0; i < 4; ++i) {
        int c = i * 256 + t; int e = c >> 4; int s = c & 15;
        uint4 v = *(const uint4*)(hbf + (size_t)(row0 + e) * HID + s * 8);
        *(uint4*)((char*)X + e * (YPITCH * 2) + s * 16) = v;
    }
    __syncthreads();

    int lane = t & 63;
    int w    = t >> 6;
    int m0 = (w & 1) * 32;
    int n0 = (w >> 1) * 64;
    int lr = lane & 15;
    int lg = lane >> 4;

    f32x4 acc[2][4];
    #pragma unroll
    for (int nf = 0; nf < 4; ++nf) {
        float bv = b1[n0 + nf * 16 + lr];
        #pragma unroll
        for (int mf = 0; mf < 2; ++mf)
            acc[mf][nf] = (f32x4){bv, bv, bv, bv};
    }
    const char* Xb = (const char*)X;
    for (int kt = 0; kt < 4; ++kt) {
        short8 a[2];
        #pragma unroll
        for (int mf = 0; mf < 2; ++mf)
            a[mf] = *(const short8*)(Xb + (m0 + mf * 16 + lr) * (YPITCH * 2)
                                        + (kt * 32 + lg * 8) * 2);
        const short* wp = Wp + (((size_t)kt * 8 + (n0 >> 4)) * 64 + lane) * 8;
        #pragma unroll
        for (int nf = 0; nf < 4; ++nf) {
            short8 bf = *(const short8*)(wp + (size_t)nf * 64 * 8);
            #pragma unroll
            for (int mf = 0; mf < 2; ++mf)
                acc[mf][nf] = __builtin_amdgcn_mfma_f32_16x16x32_bf16(
                    a[mf], bf, acc[mf][nf], 0, 0, 0);
        }
    }
    #pragma unroll
    for (int mf = 0; mf < 2; ++mf)
        #pragma unroll
        for (int r = 0; r < 4; ++r) {
            int row = m0 + mf * 16 + lg * 4 + r;
            #pragma unroll
            for (int nf = 0; nf < 4; ++nf)
                Y[(size_t)(row0 + row) * HID + n0 + nf * 16 + lr]
                    = f2bf(acc[mf][nf][r]);
        }
}

// ===== edge MLP (MFMA) over dst-sorted edges, K=160 (h_src|ef), Y[dst] init,
// ===== bf16 message tile + segment-reduced scatter.  64 edges / block ======
__global__ __launch_bounds__(256, 6)
void edge_mfma_csr_kernel(const short* __restrict__ hbf,
                          const short* __restrict__ efs,
                          const uint_t* __restrict__ meta,
                          const short* __restrict__ Y,
                          const short* __restrict__ W1p,  // KT=5
                          const short* __restrict__ W2p,  // KT=4
                          const float* __restrict__ b2,
                          float* __restrict__ agg) {
    // one buffer, aliased phases: X (bf16 64xXP) -> P/msg (bf16 64xPP)
    __shared__ short X[64 * XP];                   // 21504 B
    __shared__ int sdst[64];
    __shared__ float smf[64];
    short* Pl = X;

    int t = threadIdx.x;
    int p0 = blockIdx.x * 64;                      // sorted-position base
    int b  = p0 >> 16;

    if (t < 64) {
        uint_t m = meta[p0 + t];
        sdst[t] = (int)((m >> 12) & 0xFFFu);
        smf[t]  = (m >> 24) ? 1.f : 0.f;
        // src staged below reads meta again (cheap, L1-hot)
    }
    __syncthreads();

    // stage h_src (cols 0..127): 64 rows x 16 chunks of 16B
    #pragma unroll
    for (int i = 0; i < 4; ++i) {
        int c = i * 256 + t; int e = c >> 4; int s = c & 15;
        int src = (int)(meta[p0 + e] & 0xFFFu);
        uint4 v = *(const uint4*)(hbf + ((size_t)b * NN + src) * HID + s * 8);
        *(uint4*)((char*)X + e * (XP * 2) + s * 16) = v;
    }
    if (t < 128) {  // bf16 edge feats (cols 128..143): contiguous 2 KB
        int e = t >> 1; int s = t & 1;
        uint4 v = *(const uint4*)(efs + (size_t)(p0 + e) * FE + s * 8);
        *(uint4*)((char*)X + e * (XP * 2) + 256 + s * 16) = v;
    }
    if (t < 128) {  // zero K-pad cols 144..159
        int e = t >> 1; int s = t & 1;
        *(uint4*)((char*)X + e * (XP * 2) + 288 + s * 16) = make_uint4(0,0,0,0);
    }

    int lane = t & 63;
    int w    = t >> 6;
    int m0 = (w & 1) * 32;
    int n0 = (w >> 1) * 64;
    int lr = lane & 15;
    int lg = lane >> 4;

    // acc init = Y[dst] (bf16 gather; dst-sorted -> L2-hot). Issued before
    // the staging barrier: these are register loads, waitcnt lands at MFMA.
    f32x4 acc[2][4];
    #pragma unroll
    for (int mf = 0; mf < 2; ++mf)
        #pragma unroll
        for (int r = 0; r < 4; ++r) {
            int row = m0 + mf * 16 + lg * 4 + r;
            const short* yp = Y + ((size_t)b * NN + sdst[row]) * HID + n0 + lr;
            #pragma unroll
            for (int nf = 0; nf < 4; ++nf)
                acc[mf][nf][r] = bf2f(yp[nf * 16]);
        }
    __syncthreads();

    // ---------------- layer 1: (64x160) @ (160x128) ----------------
    const char* Xb = (const char*)X;
    for (int kt = 0; kt < 5; ++kt) {
        short8 a[2];
        #pragma unroll
        for (int mf = 0; mf < 2; ++mf)
            a[mf] = *(const short8*)(Xb + (m0 + mf * 16 + lr) * (XP * 2)
                                        + (kt * 32 + lg * 8) * 2);
        const short* wp = W1p + (((size_t)kt * 8 + (n0 >> 4)) * 64 + lane) * 8;
        #pragma unroll
        for (int nf = 0; nf < 4; ++nf) {
            short8 bf = *(const short8*)(wp + (size_t)nf * 64 * 8);
            #pragma unroll
            for (int mf = 0; mf < 2; ++mf)
                acc[mf][nf] = __builtin_amdgcn_mfma_f32_16x16x32_bf16(
                    a[mf], bf, acc[mf][nf], 0, 0, 0);
        }
    }
    __syncthreads();   // done reading X; overwrite with P

    #pragma unroll
    for (int mf = 0; mf < 2; ++mf)
        #pragma unroll
        for (int nf = 0; nf < 4; ++nf)
            #pragma unroll
            for (int r = 0; r < 4; ++r) {
                int row = m0 + mf * 16 + lg * 4 + r;
                int col = n0 + nf * 16 + lr;
                Pl[row * PP + col] = f2bf(silu(acc[mf][nf][r]));
            }
    __syncthreads();

    // ---------------- layer 2: (64x128) @ (128x128) ----------------
    f32x4 acc2[2][4];
    #pragma unroll
    for (int nf = 0; nf < 4; ++nf) {
        float bv = b2[n0 + nf * 16 + lr];
        #pragma unroll
        for (int mf = 0; mf < 2; ++mf)
            acc2[mf][nf] = (f32x4){bv, bv, bv, bv};
    }
    const char* Pb = (const char*)Pl;
    for (int kt = 0; kt < 4; ++kt) {
        short8 a[2];
        #pragma unroll
        for (int mf = 0; mf < 2; ++mf)
            a[mf] = *(const short8*)(Pb + (m0 + mf * 16 + lr) * (PP * 2)
                                        + (kt * 32 + lg * 8) * 2);
        const short* wp = W2p + (((size_t)kt * 8 + (n0 >> 4)) * 64 + lane) * 8;
        #pragma unroll
        for (int nf = 0; nf < 4; ++nf) {
            short8 bf = *(const short8*)(wp + (size_t)nf * 64 * 8);
            #pragma unroll
            for (int mf = 0; mf < 2; ++mf)
                acc2[mf][nf] = __builtin_amdgcn_mfma_f32_16x16x32_bf16(
                    a[mf], bf, acc2[mf][nf], 0, 0, 0);
        }
    }
    __syncthreads();   // done reading P; overwrite with bf16 message tile

    #pragma unroll
    for (int mf = 0; mf < 2; ++mf)
        #pragma unroll
        for (int r = 0; r < 4; ++r) {
            int row = m0 + mf * 16 + lg * 4 + r;
            float m = smf[row];
            #pragma unroll
            for (int nf = 0; nf < 4; ++nf)
                Pl[row * PP + n0 + nf * 16 + lr] = f2bf(acc2[mf][nf][r] * m);
        }
    __syncthreads();

    // segment-reduce contiguous same-dst rows; one atomic per segment
    {
        int half = t >> 7;            // rows 0..31 or 32..63
        int c    = t & 127;
        int r0 = half * 32, r1 = r0 + 32;
        float run = 0.f;
        int cur = sdst[r0];
        for (int r = r0; r < r1; ++r) {
            int d = sdst[r];          // wave-uniform
            if (d != cur) {
                atomicAdd(&agg[((size_t)b * NN + cur) * HID + c], run);
                run = 0.f; cur = d;
            }
            run += bf2f(Pl[r * PP + c]);
        }
        atomicAdd(&agg[((size_t)b * NN + cur) * HID + c], run);
    }
}

// ------------- node MLP (MFMA) + residual + mask.  64 rows / block ---------
__global__ __launch_bounds__(256, 4)
void node_mfma_kernel(const short* __restrict__ hbf_in,
                      const float* __restrict__ agg,
                      const int* __restrict__ nmask,
                      const short* __restrict__ W1p,
                      const short* __restrict__ W2p,
                      const float* __restrict__ b1,
                      const float* __restrict__ b2,
                      float* __restrict__ hout,
                      short* __restrict__ hbf_out) {
    __shared__ short X[64 * XNP];
    __shared__ int smk[64];
    short* Pl = X;

    int t = threadIdx.x;
    int row0 = blockIdx.x * 64;
    int b  = row0 >> 12;
    int nn0 = row0 & (NN - 1);

    if (t < 64) smk[t] = nmask[row0 + t];

    #pragma unroll
    for (int i = 0; i < 4; ++i) {
        int c = i * 256 + t; int e = c >> 4; int s = c & 15;
        uint4 v = *(const uint4*)(hbf_in + (size_t)(row0 + e) * HID + s * 8);
        *(uint4*)((char*)X + e * (XNP * 2) + s * 16) = v;
    }
    #pragma unroll
    for (int i = 0; i < 8; ++i) {
        int c = i * 256 + t; int e = c >> 5; int s = c & 31;
        float4 f = *(const float4*)(agg + (size_t)(row0 + e) * HID + s * 4);
        short v[4] = { f2bf(f.x), f2bf(f.y), f2bf(f.z), f2bf(f.w) };
        *(uint2*)((char*)X + e * (XNP * 2) + 256 + s * 8) = *(uint2*)v;
    }
    __syncthreads();

    int lane = t & 63;
    int w    = t >> 6;
    int m0 = (w & 1) * 32;
    int n0 = (w >> 1) * 64;
    int lr = lane & 15;
    int lg = lane >> 4;

    f32x4 acc[2][4];
    #pragma unroll
    for (int nf = 0; nf < 4; ++nf) {
        float bv = b1[n0 + nf * 16 + lr];
        #pragma unroll
        for (int mf = 0; mf < 2; ++mf)
            acc[mf][nf] = (f32x4){bv, bv, bv, bv};
    }
    const char* Xb = (const char*)X;
    for (int kt = 0; kt < 8; ++kt) {
        short8 a[2];
        #pragma unroll
        for (int mf = 0; mf < 2; ++mf)
            a[mf] = *(const short8*)(Xb + (m0 + mf * 16 + lr) * (XNP * 2)
                                        + (kt * 32 + lg * 8) * 2);
        const short* wp = W1p + (((size_t)kt * 8 + (n0 >> 4)) * 64 + lane) * 8;
        #pragma unroll
        for (int nf = 0; nf < 4; ++nf) {
            short8 bf = *(const short8*)(wp + (size_t)nf * 64 * 8);
            #pragma unroll
            for (int mf = 0; mf < 2; ++mf)
                acc[mf][nf] = __builtin_amdgcn_mfma_f32_16x16x32_bf16(
                    a[mf], bf, acc[mf][nf], 0, 0, 0);
        }
    }
    __syncthreads();

    #pragma unroll
    for (int mf = 0; mf < 2; ++mf)
        #pragma unroll
        for (int nf = 0; nf < 4; ++nf)
            #pragma unroll
            for (int r = 0; r < 4; ++r) {
                int row = m0 + mf * 16 + lg * 4 + r;
                int col = n0 + nf * 16 + lr;
                Pl[row * PP + col] = f2bf(silu(acc[mf][nf][r]));
            }
    __syncthreads();

    f32x4 acc2[2][4];
    #pragma unroll
    for (int nf = 0; nf < 4; ++nf) {
        float bv = b2[n0 + nf * 16 + lr];
        #pragma unroll
        for (int mf = 0; mf < 2; ++mf)
            acc2[mf][nf] = (f32x4){bv, bv, bv, bv};
    }
    const char* Pb = (const char*)Pl;
    for (int kt = 0; kt < 4; ++kt) {
        short8 a[2];
        #pragma unroll
        for (int mf = 0; mf < 2; ++mf)
            a[mf] = *(const short8*)(Pb + (m0 + mf * 16 + lr) * (PP * 2)
                                        + (kt * 32 + lg * 8) * 2);
        const short* wp = W2p + (((size_t)kt * 8 + (n0 >> 4)) * 64 + lane) * 8;
        #pragma unroll
        for (int nf = 0; nf < 4; ++nf) {
            short8 bf = *(const short8*)(wp + (size_t)nf * 64 * 8);
            #pragma unroll
            for (int mf = 0; mf < 2; ++mf)
                acc2[mf][nf] = __builtin_amdgcn_mfma_f32_16x16x32_bf16(
                    a[mf], bf, acc2[mf][nf], 0, 0, 0);
        }
    }

    #pragma unroll
    for (int mf = 0; mf < 2; ++mf)
        #pragma unroll
        for (int r = 0; r < 4; ++r) {
            int rl = m0 + mf * 16 + lg * 4 + r;
            float m = smk[rl] ? 1.f : 0.f;
            size_t ho = hrow(b, nn0 + rl);
            size_t hb = (size_t)(row0 + rl) * HID;
            #pragma unroll
            for (int nf = 0; nf < 4; ++nf) {
                int col = n0 + nf * 16 + lr;
                float hold = hout[ho + col];
                float hn = (hold + acc2[mf][nf][r]) * m;
                hout[ho + col] = hn;
                hbf_out[hb + col] = f2bf(hn);
            }
        }
}

extern "C" void kernel_launch(void* const* d_in, const int* in_sizes, int n_in,
                              void* d_out, int out_size, void* d_ws, size_t ws_size,
                              hipStream_t stream) {
    const float* nodes     = (const float*)d_in[0];
    const float* edge_feat = (const float*)d_in[1];
    const int*   edges     = (const int*)d_in[2];
    const int*   node_mask = (const int*)d_in[3];
    const int*   edge_mask = (const int*)d_in[4];
    const float* W_node    = (const float*)d_in[5];
    const float* W_edge    = (const float*)d_in[6];
    const float* marker    = (const float*)d_in[7];
    const float* eW1       = (const float*)d_in[8];
    const float* eb1       = (const float*)d_in[9];
    const float* eW2       = (const float*)d_in[10];
    const float* eb2       = (const float*)d_in[11];
    const float* nW1       = (const float*)d_in[12];
    const float* nb1       = (const float*)d_in[13];
    const float* nW2       = (const float*)d_in[14];
    const float* nb2       = (const float*)d_in[15];
    float* out = (float*)d_out;

    const size_t HN = (size_t)BB * NN * HID;        // 2,097,152
    char* wsb = (char*)d_ws;
    float*  agg    = (float*)wsb;   wsb += HN * 4;
    short*  hbf    = (short*)wsb;   wsb += HN * 2;
    short*  Yb     = (short*)wsb;   wsb += HN * 2;
    float*  Wec    = (float*)wsb;   wsb += 3 * 16 * HID * 4;
    short*  W1p    = (short*)wsb;   wsb += 3 * 5 * 4096 * 2;
    short*  W2p    = (short*)wsb;   wsb += 3 * 4 * 4096 * 2;
    short*  eYp    = (short*)wsb;   wsb += 3 * 4 * 4096 * 2;
    short*  nW1p   = (short*)wsb;   wsb += 3 * 8 * 4096 * 2;
    short*  nW2p   = (short*)wsb;   wsb += 3 * 4 * 4096 * 2;
    uint_t* cnt    = (uint_t*)wsb;  wsb += (size_t)BB * NN * 4;
    uint_t* cursor = (uint_t*)wsb;  wsb += (size_t)BB * NN * 4;
    uint_t* eidx   = (uint_t*)wsb;  wsb += (size_t)BB * EE * 4;
    uint_t* meta   = (uint_t*)wsb;  wsb += (size_t)BB * EE * 4;
    short*  efs    = (short*)wsb;   wsb += (size_t)BB * EE * FE * 2;
    if ((size_t)(wsb - (char*)d_ws) > ws_size) return;  // clean fail

    // ---- prolog (once per call) ----
    proj_nodes_kernel<<<(BB * NN) / 8, 128, 0, stream>>>(nodes, W_node, out, hbf);
    fuse_wec_kernel<<<48, 128, 0, stream>>>(W_edge, eW1, Wec);
    marker_kernel<<<1, 512, 0, stream>>>(marker, out);
    pack_e1_kernel<<<3 * 5 * 8, 64, 0, stream>>>(eW1, Wec, W1p);
    pack_w_kernel<<<3 * 4 * 8, 64, 0, stream>>>(eW2, W2p, 4, HID * HID);
    pack_w_kernel<<<3 * 4 * 8, 64, 0, stream>>>(eW1 + (size_t)128 * HID, eYp,
                                                4, 384 * HID);
    pack_w_kernel<<<3 * 8 * 8, 64, 0, stream>>>(nW1, nW1p, 8, 2 * HID * HID);
    pack_w_kernel<<<3 * 4 * 8, 64, 0, stream>>>(nW2, nW2p, 4, HID * HID);

    // counting sort of edges by (b, dst), then pre-permute edge data
    hipMemsetAsync(cnt, 0, (size_t)BB * NN * 4, stream);
    hist_kernel<<<(BB * EE) / 256, 256, 0, stream>>>(edges, cnt);
    scan_kernel<<<1, 256, 0, stream>>>(cnt, cursor);
    scatter_kernel<<<(BB * EE) / 256, 256, 0, stream>>>(edges, cursor, eidx);
    permute_kernel<<<(BB * EE) / 256, 256, 0, stream>>>(
        edges, edge_mask, edge_feat, eidx, meta, efs);

    for (int r = 0; r < NROUNDS; ++r) {
        hipMemsetAsync(agg, 0, HN * sizeof(float), stream);
        proj_y_kernel<<<(BB * NN) / 64, 256, 0, stream>>>(
            hbf, eYp + (size_t)r * 4 * 4096, eb1 + r * HID, Yb);
        edge_mfma_csr_kernel<<<(BB * EE) / 64, 256, 0, stream>>>(
            hbf, efs, meta, Yb,
            W1p + (size_t)r * 5 * 4096,
            W2p + (size_t)r * 4 * 4096,
            eb2 + r * HID,
            agg);
        node_mfma_kernel<<<(BB * NN) / 64, 256, 0, stream>>>(
            hbf, agg, node_mask,
            nW1p + (size_t)r * 8 * 4096,
            nW2p + (size_t)r * 4 * 4096,
            nb1 + r * HID,
            nb2 + r * HID,
            out, hbf);
    }
}

// Round 8
// 239.505 us; speedup vs baseline: 1.3197x; 1.1574x over previous
//
#include <hip/hip_runtime.h>
#include <hip/hip_bf16.h>
#include <cstdint>
#include <cstddef>

#define BB 4
#define NN 4096
#define EE 65536
#define HID 128
#define FN 32
#define FE 16
#define NROUNDS 3

#define XP 168   // edge X row pitch (bf16): 128 h_src + 16 ef + 16 zero-pad + 8
#define XNP 264  // node X row pitch (bf16): 256 data + 8 pad
#define PP 136   // P / message row pitch (bf16): 128 data + 8 pad
#define YPITCH 136

typedef __attribute__((ext_vector_type(8))) short short8;
typedef __attribute__((ext_vector_type(4))) float f32x4;
typedef unsigned int uint_t;

// h lives inside d_out: node n of batch b at out[(b*(NN+1) + 1 + n)*HID + j].
__device__ __forceinline__ size_t hrow(int b, int n) {
    return ((size_t)b * (NN + 1) + 1 + n) * HID;
}

// compiler-emitted bf16 convert (v_cvt path) — m240: faster than manual RNE
__device__ __forceinline__ short f2bf(float f) {
    __hip_bfloat16 h = __float2bfloat16(f);
    return *reinterpret_cast<short*>(&h);
}

__device__ __forceinline__ float bf2f(short s) {
    union { uint32_t u; float f; } v;
    v.u = ((uint32_t)(unsigned short)s) << 16;
    return v.f;
}

__device__ __forceinline__ float silu(float x) {
    return x * __builtin_amdgcn_rcpf(1.0f + __expf(-x));
}

__device__ __forceinline__ int clipn(int x) {
    return x < 0 ? 0 : (x > NN - 1 ? NN - 1 : x);
}

// ---- h0 = nodes @ W_node (+ folded: marker rows, cnt zero, Wec fold) ------
__global__ void proj_nodes_kernel(const float* __restrict__ nodes,
                                  const float* __restrict__ Wn,
                                  float* __restrict__ hbuf,
                                  short* __restrict__ hbf,
                                  const float* __restrict__ marker,
                                  const float* __restrict__ We,
                                  const float* __restrict__ eW1,
                                  float* __restrict__ Wec,
                                  uint_t* __restrict__ cnt) {
    __shared__ float nd[8][FN];
    int t = threadIdx.x;
    int row0 = blockIdx.x * 8;

    // ---- folded side work on spare parallel blocks ----
    if (blockIdx.x < 4) {                       // marker rows of out
        hbuf[((size_t)blockIdx.x * (NN + 1)) * HID + t] = marker[t];
    } else if (blockIdx.x < 68) {               // zero sort histogram
        int base = (blockIdx.x - 4) * 256 + t * 2;
        cnt[base] = 0u; cnt[base + 1] = 0u;
    } else if (blockIdx.x < 116) {              // Wec = W_edge @ eW1[256:384]
        int lb = blockIdx.x - 68; int r = lb >> 4; int i = lb & 15;
        const float* w1 = eW1 + ((size_t)r * 384 + 256) * HID;
        float acc = 0.f;
        for (int k = 0; k < HID; ++k)
            acc += We[i * HID + k] * w1[k * HID + t];
        Wec[((size_t)r * 16 + i) * HID + t] = acc;
    }

    for (int i = 0; i < 2; ++i) {
        int idx = i * 128 + t; int r = idx >> 5; int c = idx & 31;
        nd[r][c] = nodes[(size_t)(row0 + r) * FN + c];
    }
    __syncthreads();
    float acc[8] = {0.f,0.f,0.f,0.f,0.f,0.f,0.f,0.f};
    #pragma unroll
    for (int k = 0; k < FN; ++k) {
        float w = Wn[k * HID + t];
        #pragma unroll
        for (int r = 0; r < 8; ++r) acc[r] += nd[r][k] * w;
    }
    #pragma unroll
    for (int r = 0; r < 8; ++r) {
        int row = row0 + r; int b = row >> 12; int n = row & (NN - 1);
        hbuf[hrow(b, n) + t] = acc[r];
        hbf[(size_t)row * HID + t] = f2bf(acc[r]);
    }
}

// ---- all weight packs in ONE kernel (block-range dispatch), 64 thr --------
__device__ __forceinline__ void pack_generic(const float* __restrict__ W,
                                             short* __restrict__ P,
                                             int KT, size_t rstrideW,
                                             int lb, int lane) {
    int nt = lb & 7;
    int kt = (lb >> 3) % KT;
    int r  = lb / (8 * KT);
    const float* Wr = W + (size_t)r * rstrideW;
    int n  = nt * 16 + (lane & 15);
    int k0 = kt * 32 + (lane >> 4) * 8;
    short v[8];
    #pragma unroll
    for (int i = 0; i < 8; ++i) v[i] = f2bf(Wr[(size_t)(k0 + i) * HID + n]);
    size_t idx = (((size_t)(r * KT + kt) * 8 + nt) * 64 + lane) * 8;
    *(uint4*)&P[idx] = *(uint4*)v;
}

__global__ void pack_all_kernel(const float* __restrict__ eW1,
                                const float* __restrict__ Wec,
                                const float* __restrict__ eW2,
                                const float* __restrict__ nW1,
                                const float* __restrict__ nW2,
                                short* __restrict__ W1p,
                                short* __restrict__ W2p,
                                short* __restrict__ eYp,
                                short* __restrict__ nW1p,
                                short* __restrict__ nW2p) {
    int lane = threadIdx.x;
    int bid = blockIdx.x;
    if (bid < 120) {                 // edge L1: K=160 = eW1[0:128] | Wec | 0
        const int KT = 5;
        int nt = bid & 7; int kt = (bid >> 3) % KT; int r = bid / (8 * KT);
        int n  = nt * 16 + (lane & 15);
        int k0 = kt * 32 + (lane >> 4) * 8;
        short v[8];
        #pragma unroll
        for (int i = 0; i < 8; ++i) {
            int k = k0 + i;
            float x;
            if (k < 128)      x = eW1[((size_t)r * 384 + k) * HID + n];
            else if (k < 144) x = Wec[((size_t)r * 16 + (k - 128)) * HID + n];
            else              x = 0.f;
            v[i] = f2bf(x);
        }
        size_t idx = (((size_t)(r * KT + kt) * 8 + nt) * 64 + lane) * 8;
        *(uint4*)&W1p[idx] = *(uint4*)v;
    } else if (bid < 216) {
        pack_generic(eW2, W2p, 4, (size_t)HID * HID, bid - 120, lane);
    } else if (bid < 312) {
        pack_generic(eW1 + (size_t)128 * HID, eYp, 4, (size_t)384 * HID,
                     bid - 216, lane);
    } else if (bid < 504) {
        pack_generic(nW1, nW1p, 8, (size_t)2 * HID * HID, bid - 312, lane);
    } else {
        pack_generic(nW2, nW2p, 4, (size_t)HID * HID, bid - 504, lane);
    }
}

// ================= counting sort of edges by (b, dst) ======================
__global__ void hist_kernel(const int* __restrict__ edges,
                            uint_t* __restrict__ cnt) {
    int i = blockIdx.x * 256 + threadIdx.x;
    int b = i >> 16;
    int d = clipn(edges[(size_t)i * 2 + 1]);
    atomicAdd(&cnt[b * NN + d], 1u);
}

__global__ void scan_kernel(const uint_t* __restrict__ cnt,
                            uint_t* __restrict__ cursor) {
    __shared__ uint_t ps[256];
    int t = threadIdx.x;
    int base = t * 64;
    uint_t s = 0;
    for (int i = 0; i < 64; ++i) s += cnt[base + i];
    ps[t] = s;
    __syncthreads();
    for (int off = 1; off < 256; off <<= 1) {
        uint_t v = (t >= off) ? ps[t - off] : 0u;
        __syncthreads();
        ps[t] += v;
        __syncthreads();
    }
    uint_t run = ps[t] - s;
    for (int i = 0; i < 64; ++i) {
        cursor[base + i] = run;
        run += cnt[base + i];
    }
}

__global__ void scatter_kernel(const int* __restrict__ edges,
                               uint_t* __restrict__ cursor,
                               uint_t* __restrict__ eidx) {
    int i = blockIdx.x * 256 + threadIdx.x;
    int b = i >> 16;
    int d = clipn(edges[(size_t)i * 2 + 1]);
    uint_t p = atomicAdd(&cursor[b * NN + d], 1u);
    eidx[p] = (uint_t)(i & (EE - 1));
}

// meta[p] = src | dst<<12 | mask<<24 ; efs[p][0..15] = bf16 edge features
__global__ void permute_kernel(const int* __restrict__ edges,
                               const int* __restrict__ emask,
                               const float* __restrict__ edge_feat,
                               const uint_t* __restrict__ eidx,
                               uint_t* __restrict__ meta,
                               short* __restrict__ efs) {
    int p = blockIdx.x * 256 + threadIdx.x;
    int b = p >> 16;
    int e = (int)eidx[p];
    int2 pr = *(const int2*)&edges[((size_t)b * EE + e) * 2];
    int s = clipn(pr.x), d = clipn(pr.y);
    uint_t mk = emask[(size_t)b * EE + e] ? 1u : 0u;
    meta[p] = (uint_t)s | ((uint_t)d << 12) | (mk << 24);
    const float* src = edge_feat + ((size_t)b * EE + e) * FE;
    short v[16];
    #pragma unroll
    for (int i = 0; i < 16; ++i) v[i] = f2bf(src[i]);
    *(uint4*)(efs + (size_t)p * FE)     = *(uint4*)v;
    *(uint4*)(efs + (size_t)p * FE + 8) = *(uint4*)(v + 8);
}

// ---- per-round: Y = h @ eW1[r][128:256] + b1 (bf16), 16 rows/block --------
// also zeroes this block's 16 rows of agg (replaces hipMemsetAsync)
__global__ __launch_bounds__(256, 6)
void proj_y_kernel(const short* __restrict__ hbf,
                   const short* __restrict__ Wp,   // packed, KT=4
                   const float* __restrict__ b1,
                   short* __restrict__ Y,
                   float* __restrict__ agg) {
    __shared__ short X[16 * YPITCH];
    int t = threadIdx.x;
    int row0 = blockIdx.x * 16;          // global node row

    // zero agg rows [row0, row0+16)
    #pragma unroll
    for (int i = 0; i < 2; ++i) {
        int c = i * 256 + t;             // 512 float4 chunks
        *(float4*)(agg + (size_t)row0 * HID + c * 4) =
            make_float4(0.f, 0.f, 0.f, 0.f);
    }

    {   // stage 16 rows of h
        int e = t >> 4; int s = t & 15;
        uint4 v = *(const uint4*)(hbf + (size_t)(row0 + e) * HID + s * 8);
        *(uint4*)((char*)X + e * (YPITCH * 2) + s * 16) = v;
    }
    __syncthreads();

    int lane = t & 63;
    int w    = t >> 6;
    int n0 = w * 32;                     // wave covers 32 cols
    int lr = lane & 15;
    int lg = lane >> 4;

    f32x4 acc[2];
    #pragma unroll
    for (int nf = 0; nf < 2; ++nf) {
        float bv = b1[n0 + nf * 16 + lr];
        acc[nf] = (f32x4){bv, bv, bv, bv};
    }
    const char* Xb = (const char*)X;
    for (int kt = 0; kt < 4; ++kt) {
        short8 a = *(const short8*)(Xb + lr * (YPITCH * 2)
                                       + (kt * 32 + lg * 8) * 2);
        const short* wp = Wp + (((size_t)kt * 8 + (n0 >> 4)) * 64 + lane) * 8;
        #pragma unroll
        for (int nf = 0; nf < 2; ++nf) {
            short8 bf = *(const short8*)(wp + (size_t)nf * 64 * 8);
            acc[nf] = __builtin_amdgcn_mfma_f32_16x16x32_bf16(a, bf, acc[nf], 0, 0, 0);
        }
    }
    #pragma unroll
    for (int r = 0; r < 4; ++r) {
        int row = lg * 4 + r;
        #pragma unroll
        for (int nf = 0; nf < 2; ++nf)
            Y[(size_t)(row0 + row) * HID + n0 + nf * 16 + lr]
                = f2bf(acc[nf][r]);
    }
}

// ===== edge MLP (MFMA) over dst-sorted edges, K=160, Y[dst] init,
// ===== bf16 message tile + segment-reduced scatter.  64 edges / block ======
__global__ __launch_bounds__(256, 6)
void edge_mfma_csr_kernel(const short* __restrict__ hbf,
                          const short* __restrict__ efs,
                          const uint_t* __restrict__ meta,
                          const short* __restrict__ Y,
                          const short* __restrict__ W1p,  // KT=5
                          const short* __restrict__ W2p,  // KT=4
                          const float* __restrict__ b2,
                          float* __restrict__ agg) {
    __shared__ short X[64 * XP];                   // 21504 B, aliased phases
    __shared__ int sdst[64];
    __shared__ float smf[64];
    short* Pl = X;

    int t = threadIdx.x;
    int p0 = blockIdx.x * 64;
    int b  = p0 >> 16;

    if (t < 64) {
        uint_t m = meta[p0 + t];
        sdst[t] = (int)((m >> 12) & 0xFFFu);
        smf[t]  = (m >> 24) ? 1.f : 0.f;
    }
    __syncthreads();

    // stage h_src (cols 0..127): 64 rows x 16 chunks of 16B
    #pragma unroll
    for (int i = 0; i < 4; ++i) {
        int c = i * 256 + t; int e = c >> 4; int s = c & 15;
        int src = (int)(meta[p0 + e] & 0xFFFu);
        uint4 v = *(const uint4*)(hbf + ((size_t)b * NN + src) * HID + s * 8);
        *(uint4*)((char*)X + e * (XP * 2) + s * 16) = v;
    }
    if (t < 128) {  // bf16 edge feats (cols 128..143)
        int e = t >> 1; int s = t & 1;
        uint4 v = *(const uint4*)(efs + (size_t)(p0 + e) * FE + s * 8);
        *(uint4*)((char*)X + e * (XP * 2) + 256 + s * 16) = v;
    }
    if (t < 128) {  // zero K-pad cols 144..159
        int e = t >> 1; int s = t & 1;
        *(uint4*)((char*)X + e * (XP * 2) + 288 + s * 16) = make_uint4(0,0,0,0);
    }

    int lane = t & 63;
    int w    = t >> 6;
    int m0 = (w & 1) * 32;
    int n0 = (w >> 1) * 64;
    int lr = lane & 15;
    int lg = lane >> 4;

    // acc init = Y[dst] (bf16 gather; dst-sorted -> L2-hot)
    f32x4 acc[2][4];
    #pragma unroll
    for (int mf = 0; mf < 2; ++mf)
        #pragma unroll
        for (int r = 0; r < 4; ++r) {
            int row = m0 + mf * 16 + lg * 4 + r;
            const short* yp = Y + ((size_t)b * NN + sdst[row]) * HID + n0 + lr;
            #pragma unroll
            for (int nf = 0; nf < 4; ++nf)
                acc[mf][nf][r] = bf2f(yp[nf * 16]);
        }
    __syncthreads();

    // ---------------- layer 1: (64x160) @ (160x128) ----------------
    const char* Xb = (const char*)X;
    for (int kt = 0; kt < 5; ++kt) {
        short8 a[2];
        #pragma unroll
        for (int mf = 0; mf < 2; ++mf)
            a[mf] = *(const short8*)(Xb + (m0 + mf * 16 + lr) * (XP * 2)
                                        + (kt * 32 + lg * 8) * 2);
        const short* wp = W1p + (((size_t)kt * 8 + (n0 >> 4)) * 64 + lane) * 8;
        #pragma unroll
        for (int nf = 0; nf < 4; ++nf) {
            short8 bf = *(const short8*)(wp + (size_t)nf * 64 * 8);
            #pragma unroll
            for (int mf = 0; mf < 2; ++mf)
                acc[mf][nf] = __builtin_amdgcn_mfma_f32_16x16x32_bf16(
                    a[mf], bf, acc[mf][nf], 0, 0, 0);
        }
    }
    __syncthreads();   // done reading X; overwrite with P

    #pragma unroll
    for (int mf = 0; mf < 2; ++mf)
        #pragma unroll
        for (int nf = 0; nf < 4; ++nf)
            #pragma unroll
            for (int r = 0; r < 4; ++r) {
                int row = m0 + mf * 16 + lg * 4 + r;
                int col = n0 + nf * 16 + lr;
                Pl[row * PP + col] = f2bf(silu(acc[mf][nf][r]));
            }
    __syncthreads();

    // ---------------- layer 2: (64x128) @ (128x128) ----------------
    f32x4 acc2[2][4];
    #pragma unroll
    for (int nf = 0; nf < 4; ++nf) {
        float bv = b2[n0 + nf * 16 + lr];
        #pragma unroll
        for (int mf = 0; mf < 2; ++mf)
            acc2[mf][nf] = (f32x4){bv, bv, bv, bv};
    }
    const char* Pb = (const char*)Pl;
    for (int kt = 0; kt < 4; ++kt) {
        short8 a[2];
        #pragma unroll
        for (int mf = 0; mf < 2; ++mf)
            a[mf] = *(const short8*)(Pb + (m0 + mf * 16 + lr) * (PP * 2)
                                        + (kt * 32 + lg * 8) * 2);
        const short* wp = W2p + (((size_t)kt * 8 + (n0 >> 4)) * 64 + lane) * 8;
        #pragma unroll
        for (int nf = 0; nf < 4; ++nf) {
            short8 bf = *(const short8*)(wp + (size_t)nf * 64 * 8);
            #pragma unroll
            for (int mf = 0; mf < 2; ++mf)
                acc2[mf][nf] = __builtin_amdgcn_mfma_f32_16x16x32_bf16(
                    a[mf], bf, acc2[mf][nf], 0, 0, 0);
        }
    }
    __syncthreads();   // done reading P; overwrite with bf16 message tile

    #pragma unroll
    for (int mf = 0; mf < 2; ++mf)
        #pragma unroll
        for (int r = 0; r < 4; ++r) {
            int row = m0 + mf * 16 + lg * 4 + r;
            float m = smf[row];
            #pragma unroll
            for (int nf = 0; nf < 4; ++nf)
                Pl[row * PP + n0 + nf * 16 + lr] = f2bf(acc2[mf][nf][r] * m);
        }
    __syncthreads();

    // segment-reduce contiguous same-dst rows; one atomic per segment
    {
        int half = t >> 7;
        int c    = t & 127;
        int r0 = half * 32, r1 = r0 + 32;
        float run = 0.f;
        int cur = sdst[r0];
        for (int r = r0; r < r1; ++r) {
            int d = sdst[r];          // wave-uniform
            if (d != cur) {
                atomicAdd(&agg[((size_t)b * NN + cur) * HID + c], run);
                run = 0.f; cur = d;
            }
            run += bf2f(Pl[r * PP + c]);
        }
        atomicAdd(&agg[((size_t)b * NN + cur) * HID + c], run);
    }
}

// ------------- node MLP (MFMA) + residual + mask.  16 rows / block ---------
__global__ __launch_bounds__(256, 6)
void node_mfma_kernel(const short* __restrict__ hbf_in,
                      const float* __restrict__ agg,
                      const int* __restrict__ nmask,
                      const short* __restrict__ W1p,  // KT=8
                      const short* __restrict__ W2p,  // KT=4
                      const float* __restrict__ b1,
                      const float* __restrict__ b2,
                      float* __restrict__ hout,
                      short* __restrict__ hbf_out) {
    __shared__ short X[16 * XNP];
    __shared__ int smk[16];
    short* Pl = X;

    int t = threadIdx.x;
    int row0 = blockIdx.x * 16;
    int b  = row0 >> 12;
    int nn0 = row0 & (NN - 1);

    if (t < 16) smk[t] = nmask[row0 + t];

    {   // stage h (bf16) cols 0..127: 16 rows x 16 chunks
        int e = t >> 4; int s = t & 15;
        uint4 v = *(const uint4*)(hbf_in + (size_t)(row0 + e) * HID + s * 8);
        *(uint4*)((char*)X + e * (XNP * 2) + s * 16) = v;
    }
    // stage agg fp32 -> bf16 cols 128..255: 16 rows x 32 chunks
    #pragma unroll
    for (int i = 0; i < 2; ++i) {
        int c = i * 256 + t; int e = c >> 5; int s = c & 31;
        float4 f = *(const float4*)(agg + (size_t)(row0 + e) * HID + s * 4);
        short v[4] = { f2bf(f.x), f2bf(f.y), f2bf(f.z), f2bf(f.w) };
        *(uint2*)((char*)X + e * (XNP * 2) + 256 + s * 8) = *(uint2*)v;
    }
    __syncthreads();

    int lane = t & 63;
    int w    = t >> 6;
    int n0 = w * 32;
    int lr = lane & 15;
    int lg = lane >> 4;

    f32x4 acc[2];
    #pragma unroll
    for (int nf = 0; nf < 2; ++nf) {
        float bv = b1[n0 + nf * 16 + lr];
        acc[nf] = (f32x4){bv, bv, bv, bv};
    }
    const char* Xb = (const char*)X;
    for (int kt = 0; kt < 8; ++kt) {
        short8 a = *(const short8*)(Xb + lr * (XNP * 2)
                                       + (kt * 32 + lg * 8) * 2);
        const short* wp = W1p + (((size_t)kt * 8 + (n0 >> 4)) * 64 + lane) * 8;
        #pragma unroll
        for (int nf = 0; nf < 2; ++nf) {
            short8 bf = *(const short8*)(wp + (size_t)nf * 64 * 8);
            acc[nf] = __builtin_amdgcn_mfma_f32_16x16x32_bf16(a, bf, acc[nf], 0, 0, 0);
        }
    }
    __syncthreads();

    #pragma unroll
    for (int nf = 0; nf < 2; ++nf)
        #pragma unroll
        for (int r = 0; r < 4; ++r) {
            int row = lg * 4 + r;
            int col = n0 + nf * 16 + lr;
            Pl[row * PP + col] = f2bf(silu(acc[nf][r]));
        }
    __syncthreads();

    f32x4 acc2[2];
    #pragma unroll
    for (int nf = 0; nf < 2; ++nf) {
        float bv = b2[n0 + nf * 16 + lr];
        acc2[nf] = (f32x4){bv, bv, bv, bv};
    }
    const char* Pb = (const char*)Pl;
    for (int kt = 0; kt < 4; ++kt) {
        short8 a = *(const short8*)(Pb + lr * (PP * 2)
                                       + (kt * 32 + lg * 8) * 2);
        const short* wp = W2p + (((size_t)kt * 8 + (n0 >> 4)) * 64 + lane) * 8;
        #pragma unroll
        for (int nf = 0; nf < 2; ++nf) {
            short8 bf = *(const short8*)(wp + (size_t)nf * 64 * 8);
            acc2[nf] = __builtin_amdgcn_mfma_f32_16x16x32_bf16(a, bf, acc2[nf], 0, 0, 0);
        }
    }

    // epilogue: h_new = (h_old_fp32 + upd) * mask; write fp32 + bf16 shadow
    #pragma unroll
    for (int r = 0; r < 4; ++r) {
        int rl = lg * 4 + r;
        float m = smk[rl] ? 1.f : 0.f;
        size_t ho = hrow(b, nn0 + rl);
        size_t hb = (size_t)(row0 + rl) * HID;
        #pragma unroll
        for (int nf = 0; nf < 2; ++nf) {
            int col = n0 + nf * 16 + lr;
            float hold = hout[ho + col];
            float hn = (hold + acc2[nf][r]) * m;
            hout[ho + col] = hn;
            hbf_out[hb + col] = f2bf(hn);
        }
    }
}

extern "C" void kernel_launch(void* const* d_in, const int* in_sizes, int n_in,
                              void* d_out, int out_size, void* d_ws, size_t ws_size,
                              hipStream_t stream) {
    const float* nodes     = (const float*)d_in[0];
    const float* edge_feat = (const float*)d_in[1];
    const int*   edges     = (const int*)d_in[2];
    const int*   node_mask = (const int*)d_in[3];
    const int*   edge_mask = (const int*)d_in[4];
    const float* W_node    = (const float*)d_in[5];
    const float* W_edge    = (const float*)d_in[6];
    const float* marker    = (const float*)d_in[7];
    const float* eW1       = (const float*)d_in[8];
    const float* eb1       = (const float*)d_in[9];
    const float* eW2       = (const float*)d_in[10];
    const float* eb2       = (const float*)d_in[11];
    const float* nW1       = (const float*)d_in[12];
    const float* nb1       = (const float*)d_in[13];
    const float* nW2       = (const float*)d_in[14];
    const float* nb2       = (const float*)d_in[15];
    float* out = (float*)d_out;

    const size_t HN = (size_t)BB * NN * HID;        // 2,097,152
    char* wsb = (char*)d_ws;
    float*  agg    = (float*)wsb;   wsb += HN * 4;
    short*  hbf    = (short*)wsb;   wsb += HN * 2;
    short*  Yb     = (short*)wsb;   wsb += HN * 2;
    float*  Wec    = (float*)wsb;   wsb += 3 * 16 * HID * 4;
    short*  W1p    = (short*)wsb;   wsb += 3 * 5 * 4096 * 2;
    short*  W2p    = (short*)wsb;   wsb += 3 * 4 * 4096 * 2;
    short*  eYp    = (short*)wsb;   wsb += 3 * 4 * 4096 * 2;
    short*  nW1p   = (short*)wsb;   wsb += 3 * 8 * 4096 * 2;
    short*  nW2p   = (short*)wsb;   wsb += 3 * 4 * 4096 * 2;
    uint_t* cnt    = (uint_t*)wsb;  wsb += (size_t)BB * NN * 4;
    uint_t* cursor = (uint_t*)wsb;  wsb += (size_t)BB * NN * 4;
    uint_t* eidx   = (uint_t*)wsb;  wsb += (size_t)BB * EE * 4;
    uint_t* meta   = (uint_t*)wsb;  wsb += (size_t)BB * EE * 4;
    short*  efs    = (short*)wsb;   wsb += (size_t)BB * EE * FE * 2;
    if ((size_t)(wsb - (char*)d_ws) > ws_size) return;  // clean fail

    // ---- prolog: 6 launches ----
    proj_nodes_kernel<<<(BB * NN) / 8, 128, 0, stream>>>(
        nodes, W_node, out, hbf, marker, W_edge, eW1, Wec, cnt);
    pack_all_kernel<<<600, 64, 0, stream>>>(
        eW1, Wec, eW2, nW1, nW2, W1p, W2p, eYp, nW1p, nW2p);
    hist_kernel<<<(BB * EE) / 256, 256, 0, stream>>>(edges, cnt);
    scan_kernel<<<1, 256, 0, stream>>>(cnt, cursor);
    scatter_kernel<<<(BB * EE) / 256, 256, 0, stream>>>(edges, cursor, eidx);
    permute_kernel<<<(BB * EE) / 256, 256, 0, stream>>>(
        edges, edge_mask, edge_feat, eidx, meta, efs);

    // ---- rounds: 3 launches each ----
    for (int r = 0; r < NROUNDS; ++r) {
        proj_y_kernel<<<(BB * NN) / 16, 256, 0, stream>>>(
            hbf, eYp + (size_t)r * 4 * 4096, eb1 + r * HID, Yb, agg);
        edge_mfma_csr_kernel<<<(BB * EE) / 64, 256, 0, stream>>>(
            hbf, efs, meta, Yb,
            W1p + (size_t)r * 5 * 4096,
            W2p + (size_t)r * 4 * 4096,
            eb2 + r * HID,
            agg);
        node_mfma_kernel<<<(BB * NN) / 16, 256, 0, stream>>>(
            hbf, agg, node_mask,
            nW1p + (size_t)r * 8 * 4096,
            nW2p + (size_t)r * 4 * 4096,
            nb1 + r * HID,
            nb2 + r * HID,
            out, hbf);
    }
}

// Round 9
// 220.101 us; speedup vs baseline: 1.4361x; 1.0882x over previous
//
#include <hip/hip_runtime.h>
#include <hip/hip_bf16.h>
#include <cstdint>
#include <cstddef>

#define BB 4
#define NN 4096
#define EE 65536
#define HID 128
#define FN 32
#define FE 16
#define NROUNDS 3

#define XP 168   // edge X row pitch (bf16): 128 h_src + 16 ef + 16 zero-pad + 8
#define XNP 264  // node X row pitch (bf16): 256 data + 8 pad
#define PP 136   // P / message row pitch (bf16): 128 data + 8 pad
#define YPITCH 136

typedef __attribute__((ext_vector_type(8))) short short8;
typedef __attribute__((ext_vector_type(4))) float f32x4;
typedef unsigned int uint_t;

// h lives inside d_out: node n of batch b at out[(b*(NN+1) + 1 + n)*HID + j].
__device__ __forceinline__ size_t hrow(int b, int n) {
    return ((size_t)b * (NN + 1) + 1 + n) * HID;
}

__device__ __forceinline__ short f2bf(float f) {
    __hip_bfloat16 h = __float2bfloat16(f);
    return *reinterpret_cast<short*>(&h);
}

__device__ __forceinline__ float bf2f(short s) {
    union { uint32_t u; float f; } v;
    v.u = ((uint32_t)(unsigned short)s) << 16;
    return v.f;
}

__device__ __forceinline__ float silu(float x) {
    return x * __builtin_amdgcn_rcpf(1.0f + __expf(-x));
}

__device__ __forceinline__ int clipn(int x) {
    return x < 0 ? 0 : (x > NN - 1 ? NN - 1 : x);
}

// ---- h0 = nodes @ W_node (+ folded: marker rows, cnt zero, Wec fold) ------
__global__ void proj_nodes_kernel(const float* __restrict__ nodes,
                                  const float* __restrict__ Wn,
                                  float* __restrict__ hbuf,
                                  short* __restrict__ hbf,
                                  const float* __restrict__ marker,
                                  const float* __restrict__ We,
                                  const float* __restrict__ eW1,
                                  float* __restrict__ Wec,
                                  uint_t* __restrict__ cnt) {
    __shared__ float nd[8][FN];
    int t = threadIdx.x;
    int row0 = blockIdx.x * 8;

    if (blockIdx.x < 4) {                       // marker rows of out
        hbuf[((size_t)blockIdx.x * (NN + 1)) * HID + t] = marker[t];
    } else if (blockIdx.x < 68) {               // zero sort histogram
        int base = (blockIdx.x - 4) * 256 + t * 2;
        cnt[base] = 0u; cnt[base + 1] = 0u;
    } else if (blockIdx.x < 116) {              // Wec = W_edge @ eW1[256:384]
        int lb = blockIdx.x - 68; int r = lb >> 4; int i = lb & 15;
        const float* w1 = eW1 + ((size_t)r * 384 + 256) * HID;
        float acc = 0.f;
        for (int k = 0; k < HID; ++k)
            acc += We[i * HID + k] * w1[k * HID + t];
        Wec[((size_t)r * 16 + i) * HID + t] = acc;
    }

    for (int i = 0; i < 2; ++i) {
        int idx = i * 128 + t; int r = idx >> 5; int c = idx & 31;
        nd[r][c] = nodes[(size_t)(row0 + r) * FN + c];
    }
    __syncthreads();
    float acc[8] = {0.f,0.f,0.f,0.f,0.f,0.f,0.f,0.f};
    #pragma unroll
    for (int k = 0; k < FN; ++k) {
        float w = Wn[k * HID + t];
        #pragma unroll
        for (int r = 0; r < 8; ++r) acc[r] += nd[r][k] * w;
    }
    #pragma unroll
    for (int r = 0; r < 8; ++r) {
        int row = row0 + r; int b = row >> 12; int n = row & (NN - 1);
        hbuf[hrow(b, n) + t] = acc[r];
        hbf[(size_t)row * HID + t] = f2bf(acc[r]);
    }
}

// ---- all weight packs in ONE kernel (block-range dispatch), 64 thr --------
__device__ __forceinline__ void pack_generic(const float* __restrict__ W,
                                             short* __restrict__ P,
                                             int KT, size_t rstrideW,
                                             int lb, int lane) {
    int nt = lb & 7;
    int kt = (lb >> 3) % KT;
    int r  = lb / (8 * KT);
    const float* Wr = W + (size_t)r * rstrideW;
    int n  = nt * 16 + (lane & 15);
    int k0 = kt * 32 + (lane >> 4) * 8;
    short v[8];
    #pragma unroll
    for (int i = 0; i < 8; ++i) v[i] = f2bf(Wr[(size_t)(k0 + i) * HID + n]);
    size_t idx = (((size_t)(r * KT + kt) * 8 + nt) * 64 + lane) * 8;
    *(uint4*)&P[idx] = *(uint4*)v;
}

__global__ void pack_all_kernel(const float* __restrict__ eW1,
                                const float* __restrict__ Wec,
                                const float* __restrict__ eW2,
                                const float* __restrict__ nW1,
                                const float* __restrict__ nW2,
                                short* __restrict__ W1p,
                                short* __restrict__ W2p,
                                short* __restrict__ eYp,
                                short* __restrict__ nW1p,
                                short* __restrict__ nW2p) {
    int lane = threadIdx.x;
    int bid = blockIdx.x;
    if (bid < 120) {                 // edge L1: K=160 = eW1[0:128] | Wec | 0
        const int KT = 5;
        int nt = bid & 7; int kt = (bid >> 3) % KT; int r = bid / (8 * KT);
        int n  = nt * 16 + (lane & 15);
        int k0 = kt * 32 + (lane >> 4) * 8;
        short v[8];
        #pragma unroll
        for (int i = 0; i < 8; ++i) {
            int k = k0 + i;
            float x;
            if (k < 128)      x = eW1[((size_t)r * 384 + k) * HID + n];
            else if (k < 144) x = Wec[((size_t)r * 16 + (k - 128)) * HID + n];
            else              x = 0.f;
            v[i] = f2bf(x);
        }
        size_t idx = (((size_t)(r * KT + kt) * 8 + nt) * 64 + lane) * 8;
        *(uint4*)&W1p[idx] = *(uint4*)v;
    } else if (bid < 216) {
        pack_generic(eW2, W2p, 4, (size_t)HID * HID, bid - 120, lane);
    } else if (bid < 312) {
        pack_generic(eW1 + (size_t)128 * HID, eYp, 4, (size_t)384 * HID,
                     bid - 216, lane);
    } else if (bid < 504) {
        pack_generic(nW1, nW1p, 8, (size_t)2 * HID * HID, bid - 312, lane);
    } else {
        pack_generic(nW2, nW2p, 4, (size_t)HID * HID, bid - 504, lane);
    }
}

// ================= counting sort of edges by (b, dst) ======================
__global__ void hist_kernel(const int* __restrict__ edges,
                            uint_t* __restrict__ cnt) {
    int i = blockIdx.x * 256 + threadIdx.x;
    int b = i >> 16;
    int2 pr = *(const int2*)&edges[(size_t)i * 2];
    int d = clipn(pr.y);
    atomicAdd(&cnt[b * NN + d], 1u);
}

// one block, 256 threads: exclusive scan of 16384 counts (vectorized)
__global__ void scan_kernel(const uint_t* __restrict__ cnt,
                            uint_t* __restrict__ cursor) {
    __shared__ uint_t ps[256];
    int t = threadIdx.x;
    const uint4* c4 = (const uint4*)cnt + (size_t)t * 16;
    uint4 v[16];
    uint_t s = 0;
    #pragma unroll
    for (int i = 0; i < 16; ++i) {
        v[i] = c4[i];
        s += v[i].x + v[i].y + v[i].z + v[i].w;
    }
    ps[t] = s;
    __syncthreads();
    for (int off = 1; off < 256; off <<= 1) {
        uint_t x = (t >= off) ? ps[t - off] : 0u;
        __syncthreads();
        ps[t] += x;
        __syncthreads();
    }
    uint_t run = ps[t] - s;
    uint4* o4 = (uint4*)cursor + (size_t)t * 16;
    #pragma unroll
    for (int i = 0; i < 16; ++i) {
        uint4 o;
        o.x = run;
        o.y = o.x + v[i].x;
        o.z = o.y + v[i].y;
        o.w = o.z + v[i].z;
        run = o.w + v[i].w;
        o4[i] = o;
    }
}

// ---- merged scatter + permute: place each edge at its sorted position -----
// meta[p] = src | dst<<12 | mask<<24 ; efs[p][0..15] = bf16 edge features
__global__ void scatter_permute_kernel(const int* __restrict__ edges,
                                       const int* __restrict__ emask,
                                       const float* __restrict__ edge_feat,
                                       uint_t* __restrict__ cursor,
                                       uint_t* __restrict__ meta,
                                       short* __restrict__ efs) {
    int i = blockIdx.x * 256 + threadIdx.x;     // global edge id
    int b = i >> 16;
    int2 pr = *(const int2*)&edges[(size_t)i * 2];
    int s = clipn(pr.x), d = clipn(pr.y);
    uint_t mk = emask[i] ? 1u : 0u;
    uint_t p = atomicAdd(&cursor[b * NN + d], 1u);   // global sorted position
    meta[p] = (uint_t)s | ((uint_t)d << 12) | (mk << 24);
    const float* src = edge_feat + (size_t)i * FE;
    short v[16];
    #pragma unroll
    for (int k = 0; k < 16; ++k) v[k] = f2bf(src[k]);
    *(uint4*)(efs + (size_t)p * FE)     = *(uint4*)v;
    *(uint4*)(efs + (size_t)p * FE + 8) = *(uint4*)(v + 8);
}

// ---- round-0 only: Y = h @ eW1[0][128:256] + b1 (bf16), 16 rows/block -----
// also zeroes this block's 16 rows of agg
__global__ __launch_bounds__(256, 6)
void proj_y_kernel(const short* __restrict__ hbf,
                   const short* __restrict__ Wp,   // packed, KT=4
                   const float* __restrict__ b1,
                   short* __restrict__ Y,
                   float* __restrict__ agg) {
    __shared__ short X[16 * YPITCH];
    int t = threadIdx.x;
    int row0 = blockIdx.x * 16;

    #pragma unroll
    for (int i = 0; i < 2; ++i) {
        int c = i * 256 + t;
        *(float4*)(agg + (size_t)row0 * HID + c * 4) =
            make_float4(0.f, 0.f, 0.f, 0.f);
    }
    {
        int e = t >> 4; int s = t & 15;
        uint4 v = *(const uint4*)(hbf + (size_t)(row0 + e) * HID + s * 8);
        *(uint4*)((char*)X + e * (YPITCH * 2) + s * 16) = v;
    }
    __syncthreads();

    int lane = t & 63;
    int w    = t >> 6;
    int n0 = w * 32;
    int lr = lane & 15;
    int lg = lane >> 4;

    f32x4 acc[2];
    #pragma unroll
    for (int nf = 0; nf < 2; ++nf) {
        float bv = b1[n0 + nf * 16 + lr];
        acc[nf] = (f32x4){bv, bv, bv, bv};
    }
    const char* Xb = (const char*)X;
    for (int kt = 0; kt < 4; ++kt) {
        short8 a = *(const short8*)(Xb + lr * (YPITCH * 2)
                                       + (kt * 32 + lg * 8) * 2);
        const short* wp = Wp + (((size_t)kt * 8 + (n0 >> 4)) * 64 + lane) * 8;
        #pragma unroll
        for (int nf = 0; nf < 2; ++nf) {
            short8 bf = *(const short8*)(wp + (size_t)nf * 64 * 8);
            acc[nf] = __builtin_amdgcn_mfma_f32_16x16x32_bf16(a, bf, acc[nf], 0, 0, 0);
        }
    }
    #pragma unroll
    for (int r = 0; r < 4; ++r) {
        int row = lg * 4 + r;
        #pragma unroll
        for (int nf = 0; nf < 2; ++nf)
            Y[(size_t)(row0 + row) * HID + n0 + nf * 16 + lr]
                = f2bf(acc[nf][r]);
    }
}

// ===== edge MLP (MFMA) over dst-sorted edges, K=160, Y[dst] init,
// ===== bf16 message tile + precomputed-segment reduce.  64 edges / block ===
__global__ __launch_bounds__(256, 6)
void edge_mfma_csr_kernel(const short* __restrict__ hbf,
                          const short* __restrict__ efs,
                          const uint_t* __restrict__ meta,
                          const short* __restrict__ Y,
                          const short* __restrict__ W1p,  // KT=5
                          const short* __restrict__ W2p,  // KT=4
                          const float* __restrict__ b2,
                          float* __restrict__ agg) {
    __shared__ short X[64 * XP];                   // 21504 B, aliased phases
    __shared__ int sdst[64];
    __shared__ float smf[64];
    __shared__ unsigned short segs[65];
    __shared__ int nseg;
    short* Pl = X;

    int t = threadIdx.x;
    int p0 = blockIdx.x * 64;
    int b  = p0 >> 16;

    if (t < 64) {                                  // wave 0 only
        uint_t m = meta[p0 + t];
        sdst[t] = (int)((m >> 12) & 0xFFFu);
        smf[t]  = (m >> 24) ? 1.f : 0.f;
        // segment boundaries via ballot on dst-change
        uint_t pm = __shfl_up(m, 1);
        int flag = (t == 0) || (((m ^ pm) & 0x00FFF000u) != 0u);
        unsigned long long mask = __ballot(flag);
        int rank = __popcll(mask & ((1ull << t) - 1ull));
        if (flag) segs[rank] = (unsigned short)t;
        if (t == 0) {
            int ns = __popcll(mask);
            nseg = ns;
            segs[ns] = 64;
        }
    }
    __syncthreads();

    // stage h_src (cols 0..127): 64 rows x 16 chunks of 16B
    #pragma unroll
    for (int i = 0; i < 4; ++i) {
        int c = i * 256 + t; int e = c >> 4; int s = c & 15;
        int src = (int)(meta[p0 + e] & 0xFFFu);
        uint4 v = *(const uint4*)(hbf + ((size_t)b * NN + src) * HID + s * 8);
        *(uint4*)((char*)X + e * (XP * 2) + s * 16) = v;
    }
    if (t < 128) {  // bf16 edge feats (cols 128..143) + zero K-pad 144..159
        int e = t >> 1; int s = t & 1;
        uint4 v = *(const uint4*)(efs + (size_t)(p0 + e) * FE + s * 8);
        *(uint4*)((char*)X + e * (XP * 2) + 256 + s * 16) = v;
        *(uint4*)((char*)X + e * (XP * 2) + 288 + s * 16) = make_uint4(0,0,0,0);
    }

    int lane = t & 63;
    int w    = t >> 6;
    int m0 = (w & 1) * 32;
    int n0 = (w >> 1) * 64;
    int lr = lane & 15;
    int lg = lane >> 4;

    // acc init = Y[dst] (bf16 gather; dst-sorted -> L2-hot)
    f32x4 acc[2][4];
    #pragma unroll
    for (int mf = 0; mf < 2; ++mf)
        #pragma unroll
        for (int r = 0; r < 4; ++r) {
            int row = m0 + mf * 16 + lg * 4 + r;
            const short* yp = Y + ((size_t)b * NN + sdst[row]) * HID + n0 + lr;
            #pragma unroll
            for (int nf = 0; nf < 4; ++nf)
                acc[mf][nf][r] = bf2f(yp[nf * 16]);
        }
    __syncthreads();

    // ---------------- layer 1: (64x160) @ (160x128) ----------------
    const char* Xb = (const char*)X;
    for (int kt = 0; kt < 5; ++kt) {
        short8 a[2];
        #pragma unroll
        for (int mf = 0; mf < 2; ++mf)
            a[mf] = *(const short8*)(Xb + (m0 + mf * 16 + lr) * (XP * 2)
                                        + (kt * 32 + lg * 8) * 2);
        const short* wp = W1p + (((size_t)kt * 8 + (n0 >> 4)) * 64 + lane) * 8;
        #pragma unroll
        for (int nf = 0; nf < 4; ++nf) {
            short8 bf = *(const short8*)(wp + (size_t)nf * 64 * 8);
            #pragma unroll
            for (int mf = 0; mf < 2; ++mf)
                acc[mf][nf] = __builtin_amdgcn_mfma_f32_16x16x32_bf16(
                    a[mf], bf, acc[mf][nf], 0, 0, 0);
        }
    }
    __syncthreads();   // done reading X; overwrite with P

    #pragma unroll
    for (int mf = 0; mf < 2; ++mf)
        #pragma unroll
        for (int nf = 0; nf < 4; ++nf)
            #pragma unroll
            for (int r = 0; r < 4; ++r) {
                int row = m0 + mf * 16 + lg * 4 + r;
                int col = n0 + nf * 16 + lr;
                Pl[row * PP + col] = f2bf(silu(acc[mf][nf][r]));
            }
    __syncthreads();

    // ---------------- layer 2: (64x128) @ (128x128) ----------------
    f32x4 acc2[2][4];
    #pragma unroll
    for (int nf = 0; nf < 4; ++nf) {
        float bv = b2[n0 + nf * 16 + lr];
        #pragma unroll
        for (int mf = 0; mf < 2; ++mf)
            acc2[mf][nf] = (f32x4){bv, bv, bv, bv};
    }
    const char* Pb = (const char*)Pl;
    for (int kt = 0; kt < 4; ++kt) {
        short8 a[2];
        #pragma unroll
        for (int mf = 0; mf < 2; ++mf)
            a[mf] = *(const short8*)(Pb + (m0 + mf * 16 + lr) * (PP * 2)
                                        + (kt * 32 + lg * 8) * 2);
        const short* wp = W2p + (((size_t)kt * 8 + (n0 >> 4)) * 64 + lane) * 8;
        #pragma unroll
        for (int nf = 0; nf < 4; ++nf) {
            short8 bf = *(const short8*)(wp + (size_t)nf * 64 * 8);
            #pragma unroll
            for (int mf = 0; mf < 2; ++mf)
                acc2[mf][nf] = __builtin_amdgcn_mfma_f32_16x16x32_bf16(
                    a[mf], bf, acc2[mf][nf], 0, 0, 0);
        }
    }
    __syncthreads();   // done reading P; overwrite with bf16 message tile

    #pragma unroll
    for (int mf = 0; mf < 2; ++mf)
        #pragma unroll
        for (int r = 0; r < 4; ++r) {
            int row = m0 + mf * 16 + lg * 4 + r;
            float m = smf[row];
            #pragma unroll
            for (int nf = 0; nf < 4; ++nf)
                Pl[row * PP + n0 + nf * 16 + lr] = f2bf(acc2[mf][nf][r] * m);
        }
    __syncthreads();

    // reduce over precomputed segments; one atomic per (segment, col)
    {
        int ns = nseg;
        for (int task = t; task < (ns << 7); task += 256) {
            int s = task >> 7;
            int c = task & 127;
            int r0 = segs[s], r1 = segs[s + 1];
            float run = 0.f;
            for (int r = r0; r < r1; ++r)
                run += bf2f(Pl[r * PP + c]);
            atomicAdd(&agg[((size_t)b * NN + sdst[r0]) * HID + c], run);
        }
    }
}

// -- node MLP (MFMA) + residual + mask; optional fused next-round Y + zero --
__global__ __launch_bounds__(256, 6)
void node_mfma_kernel(const short* __restrict__ hbf_in,
                      const float* __restrict__ agg,
                      const int* __restrict__ nmask,
                      const short* __restrict__ W1p,  // KT=8
                      const short* __restrict__ W2p,  // KT=4
                      const float* __restrict__ b1,
                      const float* __restrict__ b2,
                      float* __restrict__ hout,
                      short* __restrict__ hbf_out,
                      short* __restrict__ Ynext,      // nullptr on last round
                      const short* __restrict__ eYpN, // packed Y-weights r+1
                      const float* __restrict__ b1N,  // eb1[r+1]
                      float* __restrict__ aggz) {
    __shared__ short X[16 * XNP];
    __shared__ int smk[16];
    short* Pl = X;

    int t = threadIdx.x;
    int row0 = blockIdx.x * 16;
    int b  = row0 >> 12;
    int nn0 = row0 & (NN - 1);

    if (t < 16) smk[t] = nmask[row0 + t];

    {   // stage h (bf16) cols 0..127
        int e = t >> 4; int s = t & 15;
        uint4 v = *(const uint4*)(hbf_in + (size_t)(row0 + e) * HID + s * 8);
        *(uint4*)((char*)X + e * (XNP * 2) + s * 16) = v;
    }
    #pragma unroll
    for (int i = 0; i < 2; ++i) {   // stage agg fp32 -> bf16 cols 128..255
        int c = i * 256 + t; int e = c >> 5; int s = c & 31;
        float4 f = *(const float4*)(agg + (size_t)(row0 + e) * HID + s * 4);
        short v[4] = { f2bf(f.x), f2bf(f.y), f2bf(f.z), f2bf(f.w) };
        *(uint2*)((char*)X + e * (XNP * 2) + 256 + s * 8) = *(uint2*)v;
    }
    __syncthreads();

    int lane = t & 63;
    int w    = t >> 6;
    int n0 = w * 32;
    int lr = lane & 15;
    int lg = lane >> 4;

    f32x4 acc[2];
    #pragma unroll
    for (int nf = 0; nf < 2; ++nf) {
        float bv = b1[n0 + nf * 16 + lr];
        acc[nf] = (f32x4){bv, bv, bv, bv};
    }
    const char* Xb = (const char*)X;
    for (int kt = 0; kt < 8; ++kt) {
        short8 a = *(const short8*)(Xb + lr * (XNP * 2)
                                       + (kt * 32 + lg * 8) * 2);
        const short* wp = W1p + (((size_t)kt * 8 + (n0 >> 4)) * 64 + lane) * 8;
        #pragma unroll
        for (int nf = 0; nf < 2; ++nf) {
            short8 bf = *(const short8*)(wp + (size_t)nf * 64 * 8);
            acc[nf] = __builtin_amdgcn_mfma_f32_16x16x32_bf16(a, bf, acc[nf], 0, 0, 0);
        }
    }
    __syncthreads();

    #pragma unroll
    for (int nf = 0; nf < 2; ++nf)
        #pragma unroll
        for (int r = 0; r < 4; ++r) {
            int row = lg * 4 + r;
            int col = n0 + nf * 16 + lr;
            Pl[row * PP + col] = f2bf(silu(acc[nf][r]));
        }
    __syncthreads();

    f32x4 acc2[2];
    #pragma unroll
    for (int nf = 0; nf < 2; ++nf) {
        float bv = b2[n0 + nf * 16 + lr];
        acc2[nf] = (f32x4){bv, bv, bv, bv};
    }
    const char* Pb = (const char*)Pl;
    for (int kt = 0; kt < 4; ++kt) {
        short8 a = *(const short8*)(Pb + lr * (PP * 2)
                                       + (kt * 32 + lg * 8) * 2);
        const short* wp = W2p + (((size_t)kt * 8 + (n0 >> 4)) * 64 + lane) * 8;
        #pragma unroll
        for (int nf = 0; nf < 2; ++nf) {
            short8 bf = *(const short8*)(wp + (size_t)nf * 64 * 8);
            acc2[nf] = __builtin_amdgcn_mfma_f32_16x16x32_bf16(a, bf, acc2[nf], 0, 0, 0);
        }
    }

    // epilogue: h_new = (h_old_fp32 + upd) * mask; fp32 + bf16 shadow
    short hn_bf[2][4];
    #pragma unroll
    for (int r = 0; r < 4; ++r) {
        int rl = lg * 4 + r;
        float m = smk[rl] ? 1.f : 0.f;
        size_t ho = hrow(b, nn0 + rl);
        size_t hb = (size_t)(row0 + rl) * HID;
        #pragma unroll
        for (int nf = 0; nf < 2; ++nf) {
            int col = n0 + nf * 16 + lr;
            float hold = hout[ho + col];
            float hn = (hold + acc2[nf][r]) * m;
            hout[ho + col] = hn;
            short hb16 = f2bf(hn);
            hbf_out[hb + col] = hb16;
            hn_bf[nf][r] = hb16;
        }
    }

    if (Ynext == nullptr) return;

    // ---- fused next-round Y = h_new @ eYpN + b1N; and zero agg rows ----
    __syncthreads();            // all waves done reading Pl (L2 A-frags)
    #pragma unroll
    for (int r = 0; r < 4; ++r) {
        int row = lg * 4 + r;
        #pragma unroll
        for (int nf = 0; nf < 2; ++nf)
            Pl[row * PP + n0 + nf * 16 + lr] = hn_bf[nf][r];
    }
    __syncthreads();

    f32x4 accy[2];
    #pragma unroll
    for (int nf = 0; nf < 2; ++nf) {
        float bv = b1N[n0 + nf * 16 + lr];
        accy[nf] = (f32x4){bv, bv, bv, bv};
    }
    for (int kt = 0; kt < 4; ++kt) {
        short8 a = *(const short8*)((const char*)Pl + lr * (PP * 2)
                                       + (kt * 32 + lg * 8) * 2);
        const short* wp = eYpN + (((size_t)kt * 8 + (n0 >> 4)) * 64 + lane) * 8;
        #pragma unroll
        for (int nf = 0; nf < 2; ++nf) {
            short8 bf = *(const short8*)(wp + (size_t)nf * 64 * 8);
            accy[nf] = __builtin_amdgcn_mfma_f32_16x16x32_bf16(a, bf, accy[nf], 0, 0, 0);
        }
    }
    #pragma unroll
    for (int r = 0; r < 4; ++r) {
        int row = lg * 4 + r;
        #pragma unroll
        for (int nf = 0; nf < 2; ++nf)
            Ynext[(size_t)(row0 + row) * HID + n0 + nf * 16 + lr]
                = f2bf(accy[nf][r]);
    }
    #pragma unroll
    for (int i = 0; i < 2; ++i) {   // zero agg rows for next round
        int c = i * 256 + t;
        *(float4*)(aggz + (size_t)row0 * HID + c * 4) =
            make_float4(0.f, 0.f, 0.f, 0.f);
    }
}

extern "C" void kernel_launch(void* const* d_in, const int* in_sizes, int n_in,
                              void* d_out, int out_size, void* d_ws, size_t ws_size,
                              hipStream_t stream) {
    const float* nodes     = (const float*)d_in[0];
    const float* edge_feat = (const float*)d_in[1];
    const int*   edges     = (const int*)d_in[2];
    const int*   node_mask = (const int*)d_in[3];
    const int*   edge_mask = (const int*)d_in[4];
    const float* W_node    = (const float*)d_in[5];
    const float* W_edge    = (const float*)d_in[6];
    const float* marker    = (const float*)d_in[7];
    const float* eW1       = (const float*)d_in[8];
    const float* eb1       = (const float*)d_in[9];
    const float* eW2       = (const float*)d_in[10];
    const float* eb2       = (const float*)d_in[11];
    const float* nW1       = (const float*)d_in[12];
    const float* nb1       = (const float*)d_in[13];
    const float* nW2       = (const float*)d_in[14];
    const float* nb2       = (const float*)d_in[15];
    float* out = (float*)d_out;

    const size_t HN = (size_t)BB * NN * HID;        // 2,097,152
    char* wsb = (char*)d_ws;
    float*  agg    = (float*)wsb;   wsb += HN * 4;
    short*  hbf    = (short*)wsb;   wsb += HN * 2;
    short*  Yb     = (short*)wsb;   wsb += HN * 2;
    float*  Wec    = (float*)wsb;   wsb += 3 * 16 * HID * 4;
    short*  W1p    = (short*)wsb;   wsb += 3 * 5 * 4096 * 2;
    short*  W2p    = (short*)wsb;   wsb += 3 * 4 * 4096 * 2;
    short*  eYp    = (short*)wsb;   wsb += 3 * 4 * 4096 * 2;
    short*  nW1p   = (short*)wsb;   wsb += 3 * 8 * 4096 * 2;
    short*  nW2p   = (short*)wsb;   wsb += 3 * 4 * 4096 * 2;
    uint_t* cnt    = (uint_t*)wsb;  wsb += (size_t)BB * NN * 4;
    uint_t* cursor = (uint_t*)wsb;  wsb += (size_t)BB * NN * 4;
    uint_t* meta   = (uint_t*)wsb;  wsb += (size_t)BB * EE * 4;
    short*  efs    = (short*)wsb;   wsb += (size_t)BB * EE * FE * 2;
    if ((size_t)(wsb - (char*)d_ws) > ws_size) return;  // clean fail

    // ---- prolog: 5 launches ----
    proj_nodes_kernel<<<(BB * NN) / 8, 128, 0, stream>>>(
        nodes, W_node, out, hbf, marker, W_edge, eW1, Wec, cnt);
    pack_all_kernel<<<600, 64, 0, stream>>>(
        eW1, Wec, eW2, nW1, nW2, W1p, W2p, eYp, nW1p, nW2p);
    hist_kernel<<<(BB * EE) / 256, 256, 0, stream>>>(edges, cnt);
    scan_kernel<<<1, 256, 0, stream>>>(cnt, cursor);
    scatter_permute_kernel<<<(BB * EE) / 256, 256, 0, stream>>>(
        edges, edge_mask, edge_feat, cursor, meta, efs);

    // round-0 Y (+ agg zero)
    proj_y_kernel<<<(BB * NN) / 16, 256, 0, stream>>>(
        hbf, eYp, eb1, Yb, agg);

    for (int r = 0; r < NROUNDS; ++r) {
        edge_mfma_csr_kernel<<<(BB * EE) / 64, 256, 0, stream>>>(
            hbf, efs, meta, Yb,
            W1p + (size_t)r * 5 * 4096,
            W2p + (size_t)r * 4 * 4096,
            eb2 + r * HID,
            agg);
        bool last = (r == NROUNDS - 1);
        node_mfma_kernel<<<(BB * NN) / 16, 256, 0, stream>>>(
            hbf, agg, node_mask,
            nW1p + (size_t)r * 8 * 4096,
            nW2p + (size_t)r * 4 * 4096,
            nb1 + r * HID,
            nb2 + r * HID,
            out, hbf,
            last ? nullptr : Yb,
            last ? eYp : eYp + (size_t)(r + 1) * 4 * 4096,
            last ? eb1 : eb1 + (size_t)(r + 1) * HID,
            agg);
    }
}